// Round 1
// baseline (1369.059 us; speedup 1.0000x reference)
//
#include <hip/hip_runtime.h>
#include <hip/hip_bf16.h>

// ---------------------------------------------------------------------------
// ConvTokenEmbedder: char-CNN (7 filters) -> 2x highway -> projection
// B=16, S=256 -> NTOK=4096 tokens; MAX_CHARS=50, CHAR_DIM=16, N_FILTERS=2048
// ---------------------------------------------------------------------------

#define NTOK 4096
#define NF   2048
#define KDIM 2048
#define HID  4096
#define PDIM 512

typedef __attribute__((ext_vector_type(4))) float floatx4;
typedef __attribute__((ext_vector_type(8))) short shortx8;

// global_load_lds: LDS dest is wave-uniform base + lane*16B (CK-style
// uintptr casts: generic->AS1 is identity, generic->AS3 is low-32 trunc).
__device__ inline void async_copy16(const void* g, void* l) {
  __builtin_amdgcn_global_load_lds(
      (const __attribute__((address_space(1))) void*)(uintptr_t)g,
      (__attribute__((address_space(3))) void*)(uint32_t)(uintptr_t)l,
      16, 0, 0);
}

// ---------------------------------------------------------------------------
// fp32 -> bf16 weight conversion
// ---------------------------------------------------------------------------
__global__ __launch_bounds__(256) void cvt_kernel(
    const float* __restrict__ s, __hip_bfloat16* __restrict__ d, int n) {
  int i = blockIdx.x * 256 + threadIdx.x;
  if (i < n) d[i] = __float2bfloat16(s[i]);
}

// ---------------------------------------------------------------------------
// Char CNN. One block per token. xs layout: [d][56] (t-contiguous) so each
// channel's time series loads as float4 ds_read_b128; accumulators for all
// output positions live in registers (acc[T]), weights register-resident.
// ---------------------------------------------------------------------------
template <int W>
__device__ inline void conv_one(const float* xs, const float* __restrict__ wrow,
                                float bias, __hip_bfloat16* hout) {
  constexpr int T = 50 - W + 1;
  float acc[T];
#pragma unroll
  for (int t = 0; t < T; ++t) acc[t] = 0.f;
#pragma unroll 1
  for (int d = 0; d < 16; ++d) {
    float xcol[52];
#pragma unroll
    for (int i = 0; i < 13; ++i) {
      float4 v = *(const float4*)(xs + d * 56 + i * 4);
      xcol[4 * i + 0] = v.x; xcol[4 * i + 1] = v.y;
      xcol[4 * i + 2] = v.z; xcol[4 * i + 3] = v.w;
    }
    float wr[W];
#pragma unroll
    for (int k = 0; k < W; ++k) wr[k] = wrow[d * W + k];
#pragma unroll
    for (int k = 0; k < W; ++k)
#pragma unroll
      for (int t = 0; t < T; ++t)
        acc[t] = fmaf(xcol[t + k], wr[k], acc[t]);
  }
  float mx = acc[0];
#pragma unroll
  for (int t = 1; t < T; ++t) mx = fmaxf(mx, acc[t]);
  *hout = __float2bfloat16(fmaxf(mx + bias, 0.f));
}

__global__ __launch_bounds__(256) void conv_kernel(
    const int* __restrict__ chars, const float* __restrict__ emb,
    const float* __restrict__ w0, const float* __restrict__ b0,
    const float* __restrict__ w1, const float* __restrict__ b1,
    const float* __restrict__ w2, const float* __restrict__ b2,
    const float* __restrict__ w3, const float* __restrict__ b3,
    const float* __restrict__ w4, const float* __restrict__ b4,
    const float* __restrict__ w5, const float* __restrict__ b5,
    const float* __restrict__ w6, const float* __restrict__ b6,
    __hip_bfloat16* __restrict__ h) {
  __shared__ __align__(16) float xs[16 * 56];
  __shared__ int cidx[50];
  int tok = blockIdx.x;
  int tid = threadIdx.x;
  if (tid < 50) cidx[tid] = chars[tok * 50 + tid];
  __syncthreads();
  for (int i = tid; i < 800; i += 256) {
    int t = i >> 4, d = i & 15;
    xs[d * 56 + t] = emb[cidx[t] * 16 + d];
  }
  __syncthreads();

  int wave = tid >> 6, lane = tid & 63;
  __hip_bfloat16* hrow = h + (size_t)tok * NF;

  // Wave->filter mapping keeps W wave-uniform (divergence only in the
  // lightest paths): wave0: f0..f4 (512 ch), wave1: f5 (512), waves2/3: f6.
  if (wave == 0) {
    if (lane < 32) conv_one<1>(xs, w0 + lane * 16, b0[lane], hrow + lane);
    if (lane < 32) conv_one<2>(xs, w1 + lane * 32, b1[lane], hrow + 32 + lane);
    conv_one<3>(xs, w2 + lane * 48, b2[lane], hrow + 64 + lane);
#pragma unroll 1
    for (int r = 0; r < 2; ++r)
      conv_one<4>(xs, w3 + (lane + 64 * r) * 64, b3[lane + 64 * r],
                  hrow + 128 + lane + 64 * r);
#pragma unroll 1
    for (int r = 0; r < 4; ++r)
      conv_one<5>(xs, w4 + (lane + 64 * r) * 80, b4[lane + 64 * r],
                  hrow + 256 + lane + 64 * r);
  } else if (wave == 1) {
#pragma unroll 1
    for (int r = 0; r < 8; ++r)
      conv_one<6>(xs, w5 + (lane + 64 * r) * 96, b5[lane + 64 * r],
                  hrow + 512 + lane + 64 * r);
  } else {
    int off = (wave - 2) * 512;
#pragma unroll 1
    for (int r = 0; r < 8; ++r)
      conv_one<7>(xs, w6 + (size_t)(off + lane + 64 * r) * 112,
                  b6[off + lane + 64 * r], hrow + 1024 + off + lane + 64 * r);
  }
}

// ---------------------------------------------------------------------------
// m97-style bf16 GEMM: C[n,m] = sum_k A[n,k]*B[m,k]. A: NxK, B: MxK (both
// bf16, K-contiguous). 128x128 block tile, 4 waves 2x2, each wave 64x64
// (4x4 MFMA 16x16x32 tiles), BK=32, global_load_lds width-16 staging.
// MODE 0: store bf16 (pre-activation p, no bias). MODE 1: fp32 + bias.
// ---------------------------------------------------------------------------
template <int MODE>
__global__ __launch_bounds__(256) void gemm_bt(
    const __hip_bfloat16* __restrict__ A, const __hip_bfloat16* __restrict__ B,
    void* __restrict__ Cv, const float* __restrict__ bias,
    int N, int M, int K) {
  __shared__ __align__(16) __hip_bfloat16 As[128 * 32];
  __shared__ __align__(16) __hip_bfloat16 Bs[128 * 32];
  int tid = threadIdx.x;
  int wave = tid >> 6, lane = tid & 63;
  int wr = wave >> 1, wc = wave & 1;
  int bn = blockIdx.y, bm = blockIdx.x;

  int srow = lane >> 2;        // staging: row within 16-row segment
  int skq  = (lane & 3) * 8;   // staging: k element offset
  int frow = lane & 15;        // fragment: row within 16
  int fkq  = (lane >> 4) * 8;  // fragment: k element offset

  floatx4 acc[4][4];
  floatx4 zero = {0.f, 0.f, 0.f, 0.f};
#pragma unroll
  for (int i = 0; i < 4; ++i)
#pragma unroll
    for (int j = 0; j < 4; ++j) acc[i][j] = zero;

  const __hip_bfloat16* Ab = A + (size_t)bn * 128 * K;
  const __hip_bfloat16* Bb = B + (size_t)bm * 128 * K;

  for (int kb = 0; kb < K; kb += 32) {
    __syncthreads();
#pragma unroll
    for (int it = 0; it < 2; ++it) {
      int seg = wave * 2 + it;  // 8 segments x 16 rows = 128 rows
      async_copy16(Ab + (size_t)(seg * 16 + srow) * K + kb + skq,
                   (char*)As + seg * 1024);
      async_copy16(Bb + (size_t)(seg * 16 + srow) * K + kb + skq,
                   (char*)Bs + seg * 1024);
    }
    __syncthreads();  // compiler emits vmcnt(0) drain before s_barrier

    shortx8 af[4], bf[4];
#pragma unroll
    for (int i = 0; i < 4; ++i)
      af[i] = *(const shortx8*)(As + (wr * 64 + i * 16 + frow) * 32 + fkq);
#pragma unroll
    for (int j = 0; j < 4; ++j)
      bf[j] = *(const shortx8*)(Bs + (wc * 64 + j * 16 + frow) * 32 + fkq);
#pragma unroll
    for (int i = 0; i < 4; ++i)
#pragma unroll
      for (int j = 0; j < 4; ++j)
        acc[i][j] =
            __builtin_amdgcn_mfma_f32_16x16x32_bf16(af[i], bf[j], acc[i][j], 0, 0, 0);
  }

  // C/D layout (m89/m91 verified): col = lane&15, row = (lane>>4)*4 + reg
  int crow0 = bn * 128 + wr * 64 + (lane >> 4) * 4;
  int ccol0 = bm * 128 + wc * 64 + (lane & 15);
#pragma unroll
  for (int i = 0; i < 4; ++i)
#pragma unroll
    for (int j = 0; j < 4; ++j) {
      int col = ccol0 + j * 16;
#pragma unroll
      for (int r = 0; r < 4; ++r) {
        int row = crow0 + i * 16 + r;
        if (MODE == 0) {
          ((__hip_bfloat16*)Cv)[(size_t)row * M + col] =
              __float2bfloat16(acc[i][j][r]);
        } else {
          ((float*)Cv)[(size_t)row * M + col] = acc[i][j][r] + bias[col];
        }
      }
    }
}

// ---------------------------------------------------------------------------
// Highway elementwise: h = g*h + (1-g)*relu(p_nl), g = sigmoid(p_g).
// Bias added here in fp32 (gate bias is 1.0 -> keep p raw in bf16).
// ---------------------------------------------------------------------------
__global__ __launch_bounds__(256) void highway_ew(
    const __hip_bfloat16* __restrict__ p, const float* __restrict__ hwb,
    __hip_bfloat16* __restrict__ h) {
  int i = blockIdx.x * 256 + threadIdx.x;  // over NTOK*NF
  if (i >= NTOK * NF) return;
  int n = i >> 11, j = i & (NF - 1);
  float pnl = __bfloat162float(p[(size_t)n * HID + j]) + hwb[j];
  float pg  = __bfloat162float(p[(size_t)n * HID + NF + j]) + hwb[NF + j];
  float g = 1.f / (1.f + expf(-pg));
  float hv = __bfloat162float(h[i]);
  float nl = fmaxf(pnl, 0.f);
  h[i] = __float2bfloat16(g * hv + (1.f - g) * nl);
}

// ---------------------------------------------------------------------------
extern "C" void kernel_launch(void* const* d_in, const int* in_sizes, int n_in,
                              void* d_out, int out_size, void* d_ws, size_t ws_size,
                              hipStream_t stream) {
  const int*   chars  = (const int*)d_in[1];
  const float* emb    = (const float*)d_in[2];
  const float* cw[7];
  const float* cb[7];
  for (int i = 0; i < 7; ++i) {
    cw[i] = (const float*)d_in[3 + 2 * i];
    cb[i] = (const float*)d_in[4 + 2 * i];
  }
  const float* hw_w0  = (const float*)d_in[17];
  const float* hw_b0  = (const float*)d_in[18];
  const float* hw_w1  = (const float*)d_in[19];
  const float* hw_b1  = (const float*)d_in[20];
  const float* proj_w = (const float*)d_in[21];
  const float* proj_b = (const float*)d_in[22];
  float* out = (float*)d_out;

  // Workspace layout (total 82 MiB):
  //   [0,16)   h    bf16 4096x2048
  //   [16,48)  p    bf16 4096x4096
  //   [48,64)  w0b  bf16 4096x2048
  //   [64,80)  w1b  bf16 4096x2048
  //   [80,82)  pwb  bf16 512x2048
  char* ws = (char*)d_ws;
  __hip_bfloat16* h   = (__hip_bfloat16*)(ws);
  __hip_bfloat16* p   = (__hip_bfloat16*)(ws + (16ull << 20));
  __hip_bfloat16* w0b = (__hip_bfloat16*)(ws + (48ull << 20));
  __hip_bfloat16* w1b = (__hip_bfloat16*)(ws + (64ull << 20));
  __hip_bfloat16* pwb = (__hip_bfloat16*)(ws + (80ull << 20));

  cvt_kernel<<<(HID * KDIM) / 256, 256, 0, stream>>>(hw_w0, w0b, HID * KDIM);
  cvt_kernel<<<(HID * KDIM) / 256, 256, 0, stream>>>(hw_w1, w1b, HID * KDIM);
  cvt_kernel<<<(PDIM * KDIM) / 256, 256, 0, stream>>>(proj_w, pwb, PDIM * KDIM);

  conv_kernel<<<NTOK, 256, 0, stream>>>(
      chars, emb, cw[0], cb[0], cw[1], cb[1], cw[2], cb[2], cw[3], cb[3],
      cw[4], cb[4], cw[5], cb[5], cw[6], cb[6], h);

  gemm_bt<0><<<dim3(HID / 128, NTOK / 128), 256, 0, stream>>>(
      h, w0b, (void*)p, nullptr, NTOK, HID, KDIM);
  highway_ew<<<(NTOK * NF) / 256, 256, 0, stream>>>(p, hw_b0, h);

  gemm_bt<0><<<dim3(HID / 128, NTOK / 128), 256, 0, stream>>>(
      h, w1b, (void*)p, nullptr, NTOK, HID, KDIM);
  highway_ew<<<(NTOK * NF) / 256, 256, 0, stream>>>(p, hw_b1, h);

  gemm_bt<1><<<dim3(PDIM / 128, NTOK / 128), 256, 0, stream>>>(
      h, pwb, (void*)out, proj_b, NTOK, PDIM, KDIM);
}

// Round 2
// 917.632 us; speedup vs baseline: 1.4919x; 1.4919x over previous
//
#include <hip/hip_runtime.h>
#include <hip/hip_bf16.h>

// ---------------------------------------------------------------------------
// ConvTokenEmbedder: char-CNN (7 filters, MFMA im2col) -> 2x highway -> proj
// B=16, S=256 -> NTOK=4096 tokens; MAX_CHARS=50, CHAR_DIM=16, N_FILTERS=2048
// R2: conv rewritten as per-width bf16 MFMA GEMM (rows=ch, cols=t, K=(k,d)),
//     max-over-t fused via lane shuffle in C-layout. Conv weights prepped to
//     bf16 [ch][k*16+d] (K padded to x32) in the p-region of d_ws (dead until
//     gemm1).
// ---------------------------------------------------------------------------

#define NTOK 4096
#define NF   2048
#define KDIM 2048
#define HID  4096
#define PDIM 512

typedef __attribute__((ext_vector_type(4))) float floatx4;
typedef __attribute__((ext_vector_type(8))) short shortx8;

__device__ inline void async_copy16(const void* g, void* l) {
  __builtin_amdgcn_global_load_lds(
      (const __attribute__((address_space(1))) void*)(uintptr_t)g,
      (__attribute__((address_space(3))) void*)(uint32_t)(uintptr_t)l,
      16, 0, 0);
}

// ---------------------------------------------------------------------------
// fp32 -> bf16 conversion (highway / proj weights)
// ---------------------------------------------------------------------------
__global__ __launch_bounds__(256) void cvt_kernel(
    const float* __restrict__ s, __hip_bfloat16* __restrict__ d, int n) {
  int i = blockIdx.x * 256 + threadIdx.x;
  if (i < n) d[i] = __float2bfloat16(s[i]);
}

// ---------------------------------------------------------------------------
// Conv weight prep: conv_w_f (n,16,w) fp32 -> Wb[ch][kp], kp = k*16+d,
// KP padded to mult-of-32 with zeros. All 7 filters in one flat buffer.
// bases(elems): f0 0, f1 1024, f2 2048, f3 6144, f4 14336, f5 38912, f6 88064
// total 219136 elems.
// ---------------------------------------------------------------------------
__global__ __launch_bounds__(256) void conv_wprep(
    const float* __restrict__ w0, const float* __restrict__ w1,
    const float* __restrict__ w2, const float* __restrict__ w3,
    const float* __restrict__ w4, const float* __restrict__ w5,
    const float* __restrict__ w6, __hip_bfloat16* __restrict__ Wb) {
  int idx = blockIdx.x * 256 + threadIdx.x;
  if (idx >= 219136) return;
  const int base[8] = {0, 1024, 2048, 6144, 14336, 38912, 88064, 219136};
  const int KPa[7] = {32, 32, 64, 64, 96, 96, 128};
  const float* srcs[7] = {w0, w1, w2, w3, w4, w5, w6};
  int f = 0;
  while (f < 6 && idx >= base[f + 1]) ++f;
  int KP = KPa[f], w = f + 1;
  int local = idx - base[f];
  int ch = local / KP, kp = local % KP;
  int d = kp & 15, k = kp >> 4;
  float v = 0.f;
  if (k < w) v = srcs[f][(size_t)ch * 16 * w + d * w + k];
  Wb[idx] = __float2bfloat16(v);
}

// ---------------------------------------------------------------------------
// MFMA conv: one block = 4 tokens (one per wave) x CHB channels.
// A = W tile (CHB x KP, shared), B = per-token im2col (TP x KP), MFMA
// 16x16x32 bf16. C layout: row=ch=(lane>>4)*4+reg, col=t=lane&15 -> max over
// t = max over j-tiles (masked t<T) then 16-lane xor-shuffle reduce.
// LDS rows padded +8 elems -> 2-way bank aliasing only (free, m136).
// ---------------------------------------------------------------------------
template <int W, int NCH, int CHB>
__global__ __launch_bounds__(256) void conv_mfma(
    const int* __restrict__ chars, const float* __restrict__ emb,
    const __hip_bfloat16* __restrict__ Wb, const float* __restrict__ bias,
    __hip_bfloat16* __restrict__ h, int hoff) {
  constexpr int T = 51 - W;                      // valid time positions
  constexpr int TP = (T > 48) ? 64 : 48;         // padded to x16
  constexpr int NT = TP / 16;
  constexpr int KP = ((16 * W + 31) / 32) * 32;  // K padded to x32
  constexpr int RS = KP + 8;                     // LDS row stride (elems)
  constexpr int NKT = KP / 32;
  constexpr int NCT = CHB / 16;

  __shared__ __align__(16) __hip_bfloat16 Ws[CHB * RS];
  __shared__ __align__(16) __hip_bfloat16 Xs[4 * TP * RS];

  int tid = threadIdx.x, wave = tid >> 6, lane = tid & 63;
  int chb = blockIdx.y * CHB;

  // --- stage W tile (global bf16 -> LDS, padded rows), all waves ---
  constexpr int NCHUNK = CHB * KP / 8;
  for (int c = tid; c < NCHUNK; c += 256) {
    int row = c / (KP / 8), c8 = c % (KP / 8);
    shortx8 v = *(const shortx8*)(Wb + (size_t)chb * KP + c * 8);
    *(shortx8*)(Ws + row * RS + c8 * 8) = v;
  }

  // --- build im2col B tile for this wave's token ---
  int tok = blockIdx.x * 4 + wave;
  __hip_bfloat16* Xw = Xs + wave * TP * RS;
  const int* ctok = chars + (size_t)tok * 50;
  constexpr int NPAIR = TP * (KP / 16);
  for (int p = lane; p < NPAIR; p += 64) {
    int t = p / (KP / 16), kk = p % (KP / 16);
    __hip_bfloat16 tmp[16];
    if (kk < W && t + kk < 50) {
      int c = ctok[t + kk];
      const float4* er = (const float4*)(emb + (size_t)c * 16);
      float4 e0 = er[0], e1 = er[1], e2 = er[2], e3 = er[3];
      tmp[0] = __float2bfloat16(e0.x);  tmp[1] = __float2bfloat16(e0.y);
      tmp[2] = __float2bfloat16(e0.z);  tmp[3] = __float2bfloat16(e0.w);
      tmp[4] = __float2bfloat16(e1.x);  tmp[5] = __float2bfloat16(e1.y);
      tmp[6] = __float2bfloat16(e1.z);  tmp[7] = __float2bfloat16(e1.w);
      tmp[8] = __float2bfloat16(e2.x);  tmp[9] = __float2bfloat16(e2.y);
      tmp[10] = __float2bfloat16(e2.z); tmp[11] = __float2bfloat16(e2.w);
      tmp[12] = __float2bfloat16(e3.x); tmp[13] = __float2bfloat16(e3.y);
      tmp[14] = __float2bfloat16(e3.z); tmp[15] = __float2bfloat16(e3.w);
    } else {
#pragma unroll
      for (int d = 0; d < 16; ++d) tmp[d] = __float2bfloat16(0.f);
    }
    *(shortx8*)(Xw + t * RS + kk * 16)     = *(const shortx8*)tmp;
    *(shortx8*)(Xw + t * RS + kk * 16 + 8) = *(const shortx8*)(tmp + 8);
  }
  __syncthreads();

  // --- MFMA main loop ---
  floatx4 acc[NCT][NT];
  floatx4 zero = {0.f, 0.f, 0.f, 0.f};
#pragma unroll
  for (int i = 0; i < NCT; ++i)
#pragma unroll
    for (int j = 0; j < NT; ++j) acc[i][j] = zero;

  int frow = lane & 15;
#pragma unroll
  for (int kt = 0; kt < NKT; ++kt) {
    int fk = kt * 32 + (lane >> 4) * 8;
    shortx8 bfr[NT];
#pragma unroll
    for (int j = 0; j < NT; ++j)
      bfr[j] = *(const shortx8*)(Xw + (j * 16 + frow) * RS + fk);
#pragma unroll
    for (int i = 0; i < NCT; ++i) {
      shortx8 afr = *(const shortx8*)(Ws + (i * 16 + frow) * RS + fk);
#pragma unroll
      for (int j = 0; j < NT; ++j)
        acc[i][j] =
            __builtin_amdgcn_mfma_f32_16x16x32_bf16(afr, bfr[j], acc[i][j], 0, 0, 0);
    }
  }

  // --- epilogue: masked max over t, shuffle-reduce, +bias, relu, store ---
  int col = lane & 15, q = lane >> 4;
  __hip_bfloat16* hrow = h + (size_t)tok * NF + hoff;
#pragma unroll
  for (int i = 0; i < NCT; ++i) {
#pragma unroll
    for (int r = 0; r < 4; ++r) {
      float v = -1e30f;
#pragma unroll
      for (int j = 0; j < NT; ++j) {
        int tj = j * 16 + col;
        if (tj < T) v = fmaxf(v, acc[i][j][r]);
      }
      v = fmaxf(v, __shfl_xor(v, 1));
      v = fmaxf(v, __shfl_xor(v, 2));
      v = fmaxf(v, __shfl_xor(v, 4));
      v = fmaxf(v, __shfl_xor(v, 8));
      if (col == 0) {
        int ch = chb + i * 16 + q * 4 + r;
        hrow[ch] = __float2bfloat16(fmaxf(v + bias[ch], 0.f));
      }
    }
  }
}

// ---------------------------------------------------------------------------
// m97-style bf16 GEMM: C[n,m] = sum_k A[n,k]*B[m,k]. 128x128 tile, BK=32,
// global_load_lds width-16. MODE 0: bf16 store. MODE 1: fp32 + bias.
// ---------------------------------------------------------------------------
template <int MODE>
__global__ __launch_bounds__(256) void gemm_bt(
    const __hip_bfloat16* __restrict__ A, const __hip_bfloat16* __restrict__ B,
    void* __restrict__ Cv, const float* __restrict__ bias,
    int N, int M, int K) {
  __shared__ __align__(16) __hip_bfloat16 As[128 * 32];
  __shared__ __align__(16) __hip_bfloat16 Bs[128 * 32];
  int tid = threadIdx.x;
  int wave = tid >> 6, lane = tid & 63;
  int wr = wave >> 1, wc = wave & 1;
  int bn = blockIdx.y, bm = blockIdx.x;

  int srow = lane >> 2;
  int skq  = (lane & 3) * 8;
  int frow = lane & 15;
  int fkq  = (lane >> 4) * 8;

  floatx4 acc[4][4];
  floatx4 zero = {0.f, 0.f, 0.f, 0.f};
#pragma unroll
  for (int i = 0; i < 4; ++i)
#pragma unroll
    for (int j = 0; j < 4; ++j) acc[i][j] = zero;

  const __hip_bfloat16* Ab = A + (size_t)bn * 128 * K;
  const __hip_bfloat16* Bb = B + (size_t)bm * 128 * K;

  for (int kb = 0; kb < K; kb += 32) {
    __syncthreads();
#pragma unroll
    for (int it = 0; it < 2; ++it) {
      int seg = wave * 2 + it;
      async_copy16(Ab + (size_t)(seg * 16 + srow) * K + kb + skq,
                   (char*)As + seg * 1024);
      async_copy16(Bb + (size_t)(seg * 16 + srow) * K + kb + skq,
                   (char*)Bs + seg * 1024);
    }
    __syncthreads();

    shortx8 af[4], bf[4];
#pragma unroll
    for (int i = 0; i < 4; ++i)
      af[i] = *(const shortx8*)(As + (wr * 64 + i * 16 + frow) * 32 + fkq);
#pragma unroll
    for (int j = 0; j < 4; ++j)
      bf[j] = *(const shortx8*)(Bs + (wc * 64 + j * 16 + frow) * 32 + fkq);
#pragma unroll
    for (int i = 0; i < 4; ++i)
#pragma unroll
      for (int j = 0; j < 4; ++j)
        acc[i][j] =
            __builtin_amdgcn_mfma_f32_16x16x32_bf16(af[i], bf[j], acc[i][j], 0, 0, 0);
  }

  int crow0 = bn * 128 + wr * 64 + (lane >> 4) * 4;
  int ccol0 = bm * 128 + wc * 64 + (lane & 15);
#pragma unroll
  for (int i = 0; i < 4; ++i)
#pragma unroll
    for (int j = 0; j < 4; ++j) {
      int c = ccol0 + j * 16;
#pragma unroll
      for (int r = 0; r < 4; ++r) {
        int row = crow0 + i * 16 + r;
        if (MODE == 0) {
          ((__hip_bfloat16*)Cv)[(size_t)row * M + c] =
              __float2bfloat16(acc[i][j][r]);
        } else {
          ((float*)Cv)[(size_t)row * M + c] = acc[i][j][r] + bias[c];
        }
      }
    }
}

// ---------------------------------------------------------------------------
// Highway elementwise: h = g*h + (1-g)*relu(p_nl), g = sigmoid(p_g).
// ---------------------------------------------------------------------------
__global__ __launch_bounds__(256) void highway_ew(
    const __hip_bfloat16* __restrict__ p, const float* __restrict__ hwb,
    __hip_bfloat16* __restrict__ h) {
  int i = blockIdx.x * 256 + threadIdx.x;
  if (i >= NTOK * NF) return;
  int n = i >> 11, j = i & (NF - 1);
  float pnl = __bfloat162float(p[(size_t)n * HID + j]) + hwb[j];
  float pg  = __bfloat162float(p[(size_t)n * HID + NF + j]) + hwb[NF + j];
  float g = 1.f / (1.f + expf(-pg));
  float hv = __bfloat162float(h[i]);
  float nl = fmaxf(pnl, 0.f);
  h[i] = __float2bfloat16(g * hv + (1.f - g) * nl);
}

// ---------------------------------------------------------------------------
extern "C" void kernel_launch(void* const* d_in, const int* in_sizes, int n_in,
                              void* d_out, int out_size, void* d_ws, size_t ws_size,
                              hipStream_t stream) {
  const int*   chars  = (const int*)d_in[1];
  const float* emb    = (const float*)d_in[2];
  const float* cw[7];
  const float* cb[7];
  for (int i = 0; i < 7; ++i) {
    cw[i] = (const float*)d_in[3 + 2 * i];
    cb[i] = (const float*)d_in[4 + 2 * i];
  }
  const float* hw_w0  = (const float*)d_in[17];
  const float* hw_b0  = (const float*)d_in[18];
  const float* hw_w1  = (const float*)d_in[19];
  const float* hw_b1  = (const float*)d_in[20];
  const float* proj_w = (const float*)d_in[21];
  const float* proj_b = (const float*)d_in[22];
  float* out = (float*)d_out;

  // Workspace (82 MiB + conv weights overlapped into p region):
  //   [0,16)   h    bf16 4096x2048
  //   [16,48)  p    bf16 4096x4096  (first 428KB doubles as convWb: conv
  //            weights are consumed before gemm1 writes p — stream-ordered)
  //   [48,64)  w0b  [64,80) w1b  [80,82) pwb
  char* ws = (char*)d_ws;
  __hip_bfloat16* h      = (__hip_bfloat16*)(ws);
  __hip_bfloat16* p      = (__hip_bfloat16*)(ws + (16ull << 20));
  __hip_bfloat16* convWb = (__hip_bfloat16*)(ws + (16ull << 20));
  __hip_bfloat16* w0b    = (__hip_bfloat16*)(ws + (48ull << 20));
  __hip_bfloat16* w1b    = (__hip_bfloat16*)(ws + (64ull << 20));
  __hip_bfloat16* pwb    = (__hip_bfloat16*)(ws + (80ull << 20));

  cvt_kernel<<<(HID * KDIM) / 256, 256, 0, stream>>>(hw_w0, w0b, HID * KDIM);
  cvt_kernel<<<(HID * KDIM) / 256, 256, 0, stream>>>(hw_w1, w1b, HID * KDIM);
  cvt_kernel<<<(PDIM * KDIM) / 256, 256, 0, stream>>>(proj_w, pwb, PDIM * KDIM);
  conv_wprep<<<(219136 + 255) / 256, 256, 0, stream>>>(
      cw[0], cw[1], cw[2], cw[3], cw[4], cw[5], cw[6], convWb);

  conv_mfma<1, 32, 32><<<dim3(1024, 1), 256, 0, stream>>>(
      chars, emb, convWb + 0, cb[0], h, 0);
  conv_mfma<2, 32, 32><<<dim3(1024, 1), 256, 0, stream>>>(
      chars, emb, convWb + 1024, cb[1], h, 32);
  conv_mfma<3, 64, 64><<<dim3(1024, 1), 256, 0, stream>>>(
      chars, emb, convWb + 2048, cb[2], h, 64);
  conv_mfma<4, 128, 64><<<dim3(1024, 2), 256, 0, stream>>>(
      chars, emb, convWb + 6144, cb[3], h, 128);
  conv_mfma<5, 256, 64><<<dim3(1024, 4), 256, 0, stream>>>(
      chars, emb, convWb + 14336, cb[4], h, 256);
  conv_mfma<6, 512, 64><<<dim3(1024, 8), 256, 0, stream>>>(
      chars, emb, convWb + 38912, cb[5], h, 512);
  conv_mfma<7, 1024, 64><<<dim3(1024, 16), 256, 0, stream>>>(
      chars, emb, convWb + 88064, cb[6], h, 1024);

  gemm_bt<0><<<dim3(HID / 128, NTOK / 128), 256, 0, stream>>>(
      h, w0b, (void*)p, nullptr, NTOK, HID, KDIM);
  highway_ew<<<(NTOK * NF) / 256, 256, 0, stream>>>(p, hw_b0, h);

  gemm_bt<0><<<dim3(HID / 128, NTOK / 128), 256, 0, stream>>>(
      h, w1b, (void*)p, nullptr, NTOK, HID, KDIM);
  highway_ew<<<(NTOK * NF) / 256, 256, 0, stream>>>(p, hw_b1, h);

  gemm_bt<1><<<dim3(PDIM / 128, NTOK / 128), 256, 0, stream>>>(
      h, pwb, (void*)out, proj_b, NTOK, PDIM, KDIM);
}

// Round 3
// 783.692 us; speedup vs baseline: 1.7469x; 1.1709x over previous
//
#include <hip/hip_runtime.h>
#include <hip/hip_bf16.h>

// ---------------------------------------------------------------------------
// ConvTokenEmbedder: char-CNN -> 2x highway -> projection
// R3: all 7 conv widths unified into ONE MFMA GEMM with K=128 (weights
//     zero-padded over k>=w). X (im2col) is implicit: B-fragments are sliding
//     16-aligned windows over the token's 50x16 embedding matrix, stored once
//     per block in LDS (row stride 24 elems: 16B-aligned, bank-stride 12 ->
//     ~2-way only). A-tiles staged per 128-ch iter via global_load_lds with a
//     source-permuted XOR swizzle so a-fragment reads are conflict-free.
//     Per-channel valid-T mask + max/bias/relu fused in epilogue.
// ---------------------------------------------------------------------------

#define NTOK 4096
#define NF   2048
#define KDIM 2048
#define HID  4096
#define PDIM 512

typedef __attribute__((ext_vector_type(4))) float floatx4;
typedef __attribute__((ext_vector_type(8))) short shortx8;

__device__ inline void async_copy16(const void* g, void* l) {
  __builtin_amdgcn_global_load_lds(
      (const __attribute__((address_space(1))) void*)(uintptr_t)g,
      (__attribute__((address_space(3))) void*)(uint32_t)(uintptr_t)l,
      16, 0, 0);
}

// ---------------------------------------------------------------------------
__global__ __launch_bounds__(256) void cvt_kernel(
    const float* __restrict__ s, __hip_bfloat16* __restrict__ d, int n) {
  int i = blockIdx.x * 256 + threadIdx.x;
  if (i < n) d[i] = __float2bfloat16(s[i]);
}

// ---------------------------------------------------------------------------
// Unified conv weight prep: Wb[ch][kp], kp = k*16+d, K padded to 128 with
// zeros for k >= width(ch). 2048x128 = 262144 elems. Bias packed after.
// ---------------------------------------------------------------------------
__global__ __launch_bounds__(256) void conv_wprep(
    const float* __restrict__ w0, const float* __restrict__ w1,
    const float* __restrict__ w2, const float* __restrict__ w3,
    const float* __restrict__ w4, const float* __restrict__ w5,
    const float* __restrict__ w6,
    const float* __restrict__ b0, const float* __restrict__ b1,
    const float* __restrict__ b2, const float* __restrict__ b3,
    const float* __restrict__ b4, const float* __restrict__ b5,
    const float* __restrict__ b6,
    __hip_bfloat16* __restrict__ Wb, float* __restrict__ Bc) {
  int idx = blockIdx.x * 256 + threadIdx.x;
  const int start[7] = {0, 32, 64, 128, 256, 512, 1024};
  const float* ws[7] = {w0, w1, w2, w3, w4, w5, w6};
  const float* bs[7] = {b0, b1, b2, b3, b4, b5, b6};
  if (idx < 262144) {
    int ch = idx >> 7, kp = idx & 127;
    int f = (ch >= 32) + (ch >= 64) + (ch >= 128) + (ch >= 256) +
            (ch >= 512) + (ch >= 1024);
    int w = f + 1, lc = ch - start[f];
    int d = kp & 15, k = kp >> 4;
    float v = (k < w) ? ws[f][((size_t)lc * 16 + d) * w + k] : 0.f;
    Wb[idx] = __float2bfloat16(v);
  } else if (idx < 262144 + 2048) {
    int ch = idx - 262144;
    int f = (ch >= 32) + (ch >= 64) + (ch >= 128) + (ch >= 256) +
            (ch >= 512) + (ch >= 1024);
    Bc[ch] = bs[f][ch - start[f]];
  }
}

// ---------------------------------------------------------------------------
// Unified conv. Block = 2 tokens; loop over 16 channel-blocks of 128.
// Waves 2x2: wr = ch-half (64 ch), wc = token. Per iter per wave:
// 4 kt x (4 a-frags + 4 b-frags + 16 MFMA).
// E in LDS: 72 rows x 24-elem stride (rows >=50 zero).
// A in LDS: 128 rows x 128 elems, chunk-XOR-swizzled at stage time.
// ---------------------------------------------------------------------------
__global__ __launch_bounds__(256) void conv_unified(
    const int* __restrict__ chars, const float* __restrict__ emb,
    const __hip_bfloat16* __restrict__ Wb, const float* __restrict__ bias,
    __hip_bfloat16* __restrict__ h) {
  __shared__ __align__(16) __hip_bfloat16 As[128 * 128];
  __shared__ __align__(16) __hip_bfloat16 Xs[2 * 72 * 24];

  int tid = threadIdx.x, wave = tid >> 6, lane = tid & 63;
  int wr = wave >> 1, wc = wave & 1;
  int frow = lane & 15, q = lane >> 4;
  int tok0 = blockIdx.x * 2;

  // --- build E (bf16, padded) for both tokens: one row per thread ---
  if (tid < 144) {
    int tk = tid / 72, r = tid % 72;
    __hip_bfloat16 tmp[16];
    if (r < 50) {
      int c = chars[(size_t)(tok0 + tk) * 50 + r];
      const float4* er = (const float4*)(emb + (size_t)c * 16);
      float4 e0 = er[0], e1 = er[1], e2 = er[2], e3 = er[3];
      tmp[0] = __float2bfloat16(e0.x);  tmp[1] = __float2bfloat16(e0.y);
      tmp[2] = __float2bfloat16(e0.z);  tmp[3] = __float2bfloat16(e0.w);
      tmp[4] = __float2bfloat16(e1.x);  tmp[5] = __float2bfloat16(e1.y);
      tmp[6] = __float2bfloat16(e1.z);  tmp[7] = __float2bfloat16(e1.w);
      tmp[8] = __float2bfloat16(e2.x);  tmp[9] = __float2bfloat16(e2.y);
      tmp[10] = __float2bfloat16(e2.z); tmp[11] = __float2bfloat16(e2.w);
      tmp[12] = __float2bfloat16(e3.x); tmp[13] = __float2bfloat16(e3.y);
      tmp[14] = __float2bfloat16(e3.z); tmp[15] = __float2bfloat16(e3.w);
    } else {
#pragma unroll
      for (int d = 0; d < 16; ++d) tmp[d] = __float2bfloat16(0.f);
    }
    *(shortx8*)(Xs + (tk * 72 + r) * 24)     = *(const shortx8*)tmp;
    *(shortx8*)(Xs + (tk * 72 + r) * 24 + 8) = *(const shortx8*)(tmp + 8);
  }

  int tok = tok0 + wc;
  const __hip_bfloat16* Xw = Xs + wc * (72 * 24);

#pragma unroll 1
  for (int y = 0; y < 16; ++y) {
    __syncthreads();  // As free (prev iter reads done); y=0: X writes ordered
    // --- stage A tile (128 ch x 128 K, 32 KB), XOR-swizzled source ---
#pragma unroll
    for (int s = 0; s < 8; ++s) {
      int R = s * 16 + wave * 4 + (lane >> 4);
      int c = lane & 15;
      int gc = c ^ (R & 7);
      async_copy16(Wb + ((size_t)(y * 128 + R) * 128 + gc * 8),
                   (char*)As + s * 4096 + wave * 1024);
    }
    __syncthreads();  // vmcnt drain

    floatx4 acc[4][4];
    floatx4 zero = {0.f, 0.f, 0.f, 0.f};
#pragma unroll
    for (int i = 0; i < 4; ++i)
#pragma unroll
      for (int j = 0; j < 4; ++j) acc[i][j] = zero;

#pragma unroll
    for (int kt = 0; kt < 4; ++kt) {
      int k2 = kt * 4 + q;                  // 16B chunk index in K
      int kk = kt * 2 + (q >> 1);           // char offset k of this frag
      int d0 = (q & 1) * 8;                 // dim offset within E row
      shortx8 bfr[4], afr[4];
#pragma unroll
      for (int j = 0; j < 4; ++j)
        bfr[j] = *(const shortx8*)(Xw + (j * 16 + frow + kk) * 24 + d0);
#pragma unroll
      for (int i = 0; i < 4; ++i) {
        int row = wr * 64 + i * 16 + frow;
        afr[i] = *(const shortx8*)(As + row * 128 + (k2 ^ (row & 7)) * 8);
      }
#pragma unroll
      for (int i = 0; i < 4; ++i)
#pragma unroll
        for (int j = 0; j < 4; ++j)
          acc[i][j] = __builtin_amdgcn_mfma_f32_16x16x32_bf16(
              afr[i], bfr[j], acc[i][j], 0, 0, 0);
    }

    // --- epilogue: per-channel masked max over t, reduce, bias, relu ---
#pragma unroll
    for (int i = 0; i < 4; ++i) {
#pragma unroll
      for (int r = 0; r < 4; ++r) {
        int ch = y * 128 + wr * 64 + i * 16 + q * 4 + r;
        int w = 1 + (ch >= 32) + (ch >= 64) + (ch >= 128) + (ch >= 256) +
                (ch >= 512) + (ch >= 1024);
        int Tv = 51 - w;
        float v = -1e30f;
#pragma unroll
        for (int j = 0; j < 4; ++j) {
          int t = j * 16 + frow;
          if (t < Tv) v = fmaxf(v, acc[i][j][r]);
        }
        v = fmaxf(v, __shfl_xor(v, 1));
        v = fmaxf(v, __shfl_xor(v, 2));
        v = fmaxf(v, __shfl_xor(v, 4));
        v = fmaxf(v, __shfl_xor(v, 8));
        if (frow == 0)
          h[(size_t)tok * NF + ch] = __float2bfloat16(fmaxf(v + bias[ch], 0.f));
      }
    }
  }
}

// ---------------------------------------------------------------------------
// m97-style bf16 GEMM: C[n,m] = sum_k A[n,k]*B[m,k]. 128x128 tile, BK=32,
// global_load_lds width-16. MODE 0: bf16 store. MODE 1: fp32 + bias.
// ---------------------------------------------------------------------------
template <int MODE>
__global__ __launch_bounds__(256) void gemm_bt(
    const __hip_bfloat16* __restrict__ A, const __hip_bfloat16* __restrict__ B,
    void* __restrict__ Cv, const float* __restrict__ bias,
    int N, int M, int K) {
  __shared__ __align__(16) __hip_bfloat16 As[128 * 32];
  __shared__ __align__(16) __hip_bfloat16 Bs[128 * 32];
  int tid = threadIdx.x;
  int wave = tid >> 6, lane = tid & 63;
  int wr = wave >> 1, wc = wave & 1;
  int bn = blockIdx.y, bm = blockIdx.x;

  int srow = lane >> 2;
  int skq  = (lane & 3) * 8;
  int frow = lane & 15;
  int fkq  = (lane >> 4) * 8;

  floatx4 acc[4][4];
  floatx4 zero = {0.f, 0.f, 0.f, 0.f};
#pragma unroll
  for (int i = 0; i < 4; ++i)
#pragma unroll
    for (int j = 0; j < 4; ++j) acc[i][j] = zero;

  const __hip_bfloat16* Ab = A + (size_t)bn * 128 * K;
  const __hip_bfloat16* Bb = B + (size_t)bm * 128 * K;

  for (int kb = 0; kb < K; kb += 32) {
    __syncthreads();
#pragma unroll
    for (int it = 0; it < 2; ++it) {
      int seg = wave * 2 + it;
      async_copy16(Ab + (size_t)(seg * 16 + srow) * K + kb + skq,
                   (char*)As + seg * 1024);
      async_copy16(Bb + (size_t)(seg * 16 + srow) * K + kb + skq,
                   (char*)Bs + seg * 1024);
    }
    __syncthreads();

    shortx8 af[4], bf[4];
#pragma unroll
    for (int i = 0; i < 4; ++i)
      af[i] = *(const shortx8*)(As + (wr * 64 + i * 16 + frow) * 32 + fkq);
#pragma unroll
    for (int j = 0; j < 4; ++j)
      bf[j] = *(const shortx8*)(Bs + (wc * 64 + j * 16 + frow) * 32 + fkq);
#pragma unroll
    for (int i = 0; i < 4; ++i)
#pragma unroll
      for (int j = 0; j < 4; ++j)
        acc[i][j] =
            __builtin_amdgcn_mfma_f32_16x16x32_bf16(af[i], bf[j], acc[i][j], 0, 0, 0);
  }

  int crow0 = bn * 128 + wr * 64 + (lane >> 4) * 4;
  int ccol0 = bm * 128 + wc * 64 + (lane & 15);
#pragma unroll
  for (int i = 0; i < 4; ++i)
#pragma unroll
    for (int j = 0; j < 4; ++j) {
      int c = ccol0 + j * 16;
#pragma unroll
      for (int r = 0; r < 4; ++r) {
        int row = crow0 + i * 16 + r;
        if (MODE == 0) {
          ((__hip_bfloat16*)Cv)[(size_t)row * M + c] =
              __float2bfloat16(acc[i][j][r]);
        } else {
          ((float*)Cv)[(size_t)row * M + c] = acc[i][j][r] + bias[c];
        }
      }
    }
}

// ---------------------------------------------------------------------------
__global__ __launch_bounds__(256) void highway_ew(
    const __hip_bfloat16* __restrict__ p, const float* __restrict__ hwb,
    __hip_bfloat16* __restrict__ h) {
  int i = blockIdx.x * 256 + threadIdx.x;
  if (i >= NTOK * NF) return;
  int n = i >> 11, j = i & (NF - 1);
  float pnl = __bfloat162float(p[(size_t)n * HID + j]) + hwb[j];
  float pg  = __bfloat162float(p[(size_t)n * HID + NF + j]) + hwb[NF + j];
  float g = 1.f / (1.f + expf(-pg));
  float hv = __bfloat162float(h[i]);
  float nl = fmaxf(pnl, 0.f);
  h[i] = __float2bfloat16(g * hv + (1.f - g) * nl);
}

// ---------------------------------------------------------------------------
extern "C" void kernel_launch(void* const* d_in, const int* in_sizes, int n_in,
                              void* d_out, int out_size, void* d_ws, size_t ws_size,
                              hipStream_t stream) {
  const int*   chars  = (const int*)d_in[1];
  const float* emb    = (const float*)d_in[2];
  const float* cw[7];
  const float* cb[7];
  for (int i = 0; i < 7; ++i) {
    cw[i] = (const float*)d_in[3 + 2 * i];
    cb[i] = (const float*)d_in[4 + 2 * i];
  }
  const float* hw_w0  = (const float*)d_in[17];
  const float* hw_b0  = (const float*)d_in[18];
  const float* hw_w1  = (const float*)d_in[19];
  const float* hw_b1  = (const float*)d_in[20];
  const float* proj_w = (const float*)d_in[21];
  const float* proj_b = (const float*)d_in[22];
  float* out = (float*)d_out;

  // Workspace (82 MiB; conv W/bias overlapped into p region, consumed
  // before gemm1 writes p — stream-ordered):
  //   [0,16)   h bf16 4096x2048 | [16,48) p bf16 4096x4096 (+convWb 520KB)
  //   [48,64)  w0b | [64,80) w1b | [80,82) pwb
  char* ws = (char*)d_ws;
  __hip_bfloat16* h      = (__hip_bfloat16*)(ws);
  __hip_bfloat16* p      = (__hip_bfloat16*)(ws + (16ull << 20));
  __hip_bfloat16* convWb = (__hip_bfloat16*)(ws + (16ull << 20));
  float*          convBc = (float*)(ws + (16ull << 20) + 524288);
  __hip_bfloat16* w0b    = (__hip_bfloat16*)(ws + (48ull << 20));
  __hip_bfloat16* w1b    = (__hip_bfloat16*)(ws + (64ull << 20));
  __hip_bfloat16* pwb    = (__hip_bfloat16*)(ws + (80ull << 20));

  cvt_kernel<<<(HID * KDIM) / 256, 256, 0, stream>>>(hw_w0, w0b, HID * KDIM);
  cvt_kernel<<<(HID * KDIM) / 256, 256, 0, stream>>>(hw_w1, w1b, HID * KDIM);
  cvt_kernel<<<(PDIM * KDIM) / 256, 256, 0, stream>>>(proj_w, pwb, PDIM * KDIM);
  conv_wprep<<<(262144 + 2048 + 255) / 256, 256, 0, stream>>>(
      cw[0], cw[1], cw[2], cw[3], cw[4], cw[5], cw[6],
      cb[0], cb[1], cb[2], cb[3], cb[4], cb[5], cb[6], convWb, convBc);

  conv_unified<<<NTOK / 2, 256, 0, stream>>>(chars, emb, convWb, convBc, h);

  gemm_bt<0><<<dim3(HID / 128, NTOK / 128), 256, 0, stream>>>(
      h, w0b, (void*)p, nullptr, NTOK, HID, KDIM);
  highway_ew<<<(NTOK * NF) / 256, 256, 0, stream>>>(p, hw_b0, h);

  gemm_bt<0><<<dim3(HID / 128, NTOK / 128), 256, 0, stream>>>(
      h, w1b, (void*)p, nullptr, NTOK, HID, KDIM);
  highway_ew<<<(NTOK * NF) / 256, 256, 0, stream>>>(p, hw_b1, h);

  gemm_bt<1><<<dim3(PDIM / 128, NTOK / 128), 256, 0, stream>>>(
      h, pwb, (void*)out, proj_b, NTOK, PDIM, KDIM);
}

// Round 4
// 736.984 us; speedup vs baseline: 1.8576x; 1.0634x over previous
//
#include <hip/hip_runtime.h>
#include <hip/hip_bf16.h>

// ---------------------------------------------------------------------------
// ConvTokenEmbedder: char-CNN -> 2x highway -> projection
// R4: conv restructured: weights register-resident per wave (loaded once),
//     tokens stream through double-buffered LDS X tiles (one barrier/step).
//     Per-segment (NKT,NT) template dispatch cuts padded FLOPs (floor 42us).
//     Highway fused into GEMM epilogue via interleaved W' rows + lane-pair
//     shfl (p never materialized; h ping-pongs between two buffers).
// ---------------------------------------------------------------------------

#define NTOK 4096
#define NF   2048
#define KDIM 2048
#define HID  4096
#define PDIM 512

typedef __attribute__((ext_vector_type(4))) float floatx4;
typedef __attribute__((ext_vector_type(8))) short shortx8;

__device__ inline void async_copy16(const void* g, void* l) {
  __builtin_amdgcn_global_load_lds(
      (const __attribute__((address_space(1))) void*)(uintptr_t)g,
      (__attribute__((address_space(3))) void*)(uint32_t)(uintptr_t)l,
      16, 0, 0);
}

// ---------------------------------------------------------------------------
__global__ __launch_bounds__(256) void cvt_kernel(
    const float* __restrict__ s, __hip_bfloat16* __restrict__ d, int n) {
  int i = blockIdx.x * 256 + threadIdx.x;
  if (i < n) d[i] = __float2bfloat16(s[i]);
}

// Highway weight cvt with nl/gate row interleave: dst row r = src row
// (r>>1) + (r&1)*2048. So cols 2j/2j+1 of p' are (nl_j, gate_j).
__global__ __launch_bounds__(256) void cvt_hw(
    const float* __restrict__ s, __hip_bfloat16* __restrict__ d) {
  int i = blockIdx.x * 256 + threadIdx.x;  // over 4096*2048
  int r = i >> 11, k = i & 2047;
  int sr = (r >> 1) + (r & 1) * 2048;
  d[i] = __float2bfloat16(s[(size_t)sr * 2048 + k]);
}

// ---------------------------------------------------------------------------
// Conv weight prep: Wb[ch][kp], kp = k*16+d, K padded to 128 (zeros k>=w).
// Plus bias pack [2048] and bf16 emb table [262*16].
// ---------------------------------------------------------------------------
__global__ __launch_bounds__(256) void conv_wprep(
    const float* __restrict__ w0, const float* __restrict__ w1,
    const float* __restrict__ w2, const float* __restrict__ w3,
    const float* __restrict__ w4, const float* __restrict__ w5,
    const float* __restrict__ w6,
    const float* __restrict__ b0, const float* __restrict__ b1,
    const float* __restrict__ b2, const float* __restrict__ b3,
    const float* __restrict__ b4, const float* __restrict__ b5,
    const float* __restrict__ b6, const float* __restrict__ emb,
    __hip_bfloat16* __restrict__ Wb, float* __restrict__ Bc,
    __hip_bfloat16* __restrict__ embb) {
  int idx = blockIdx.x * 256 + threadIdx.x;
  const int start[7] = {0, 32, 64, 128, 256, 512, 1024};
  const float* ws[7] = {w0, w1, w2, w3, w4, w5, w6};
  const float* bs[7] = {b0, b1, b2, b3, b4, b5, b6};
  if (idx < 262144) {
    int ch = idx >> 7, kp = idx & 127;
    int f = (ch >= 32) + (ch >= 64) + (ch >= 128) + (ch >= 256) +
            (ch >= 512) + (ch >= 1024);
    int w = f + 1, lc = ch - start[f];
    int d = kp & 15, k = kp >> 4;
    float v = (k < w) ? ws[f][((size_t)lc * 16 + d) * w + k] : 0.f;
    Wb[idx] = __float2bfloat16(v);
  } else if (idx < 262144 + 2048) {
    int ch = idx - 262144;
    int f = (ch >= 32) + (ch >= 64) + (ch >= 128) + (ch >= 256) +
            (ch >= 512) + (ch >= 1024);
    Bc[ch] = bs[f][ch - start[f]];
  } else if (idx < 262144 + 2048 + 4192) {
    int e = idx - 262144 - 2048;
    embb[e] = __float2bfloat16(emb[e]);
  }
}

// ---------------------------------------------------------------------------
// Conv body. Block: 128 channels (chb) x 32 tokens. Waves 2x2 (wr=ch-half,
// wc=token-of-pair). a-frags register-resident (loaded once from global Wb).
// X: 2 tokens x 72 rows x 24-elem stride, double-buffered; one gather per
// staging thread from bf16 emb table. One __syncthreads per 2-token step.
// Epilogue: masked max over t, 16-lane shfl reduce, bias, relu.
// ---------------------------------------------------------------------------
template <int NKT, int NT>
__device__ __forceinline__ void conv_body(
    const int* __restrict__ chars, const __hip_bfloat16* __restrict__ embb,
    const __hip_bfloat16* __restrict__ Wb, const float* __restrict__ bias,
    __hip_bfloat16* __restrict__ h, int chb,
    __hip_bfloat16 (*Xs)[2][72 * 24]) {
  int tid = threadIdx.x, wave = tid >> 6, lane = tid & 63;
  int wr = wave >> 1, wc = wave & 1;
  int frow = lane & 15, q = lane >> 4;
  int tokbase = blockIdx.x * 32;

  shortx8 afr[NKT][4];
#pragma unroll
  for (int kt = 0; kt < NKT; ++kt)
#pragma unroll
    for (int i = 0; i < 4; ++i)
      afr[kt][i] = *(const shortx8*)(
          Wb + (size_t)(chb + wr * 64 + i * 16 + frow) * 128 + (kt * 4 + q) * 8);

  // stage pair 0
  if (tid < 144) {
    int tk = (tid >= 72) ? 1 : 0, r = tid - tk * 72;
    shortx8 v0 = {0, 0, 0, 0, 0, 0, 0, 0}, v1 = {0, 0, 0, 0, 0, 0, 0, 0};
    if (r < 50) {
      int c = chars[(size_t)tokbase * 50 + tk * 50 + r];
      const shortx8* e = (const shortx8*)(embb + c * 16);
      v0 = e[0]; v1 = e[1];
    }
    *(shortx8*)(&Xs[0][tk][r * 24]) = v0;
    *(shortx8*)(&Xs[0][tk][r * 24 + 8]) = v1;
  }
  __syncthreads();

#pragma unroll 1
  for (int g = 0; g < 16; ++g) {
    if (g < 15 && tid < 144) {
      int tk = (tid >= 72) ? 1 : 0, r = tid - tk * 72;
      shortx8 v0 = {0, 0, 0, 0, 0, 0, 0, 0}, v1 = {0, 0, 0, 0, 0, 0, 0, 0};
      if (r < 50) {
        int c = chars[(size_t)(tokbase + 2 * g + 2) * 50 + tk * 50 + r];
        const shortx8* e = (const shortx8*)(embb + c * 16);
        v0 = e[0]; v1 = e[1];
      }
      *(shortx8*)(&Xs[(g + 1) & 1][tk][r * 24]) = v0;
      *(shortx8*)(&Xs[(g + 1) & 1][tk][r * 24 + 8]) = v1;
    }

    const __hip_bfloat16* Xw = &Xs[g & 1][wc][0];
    floatx4 acc[4][NT];
    floatx4 zero = {0.f, 0.f, 0.f, 0.f};
#pragma unroll
    for (int i = 0; i < 4; ++i)
#pragma unroll
      for (int j = 0; j < NT; ++j) acc[i][j] = zero;

#pragma unroll
    for (int kt = 0; kt < NKT; ++kt) {
      int kk = kt * 2 + (q >> 1);
      int d0 = (q & 1) * 8;
#pragma unroll
      for (int j = 0; j < NT; ++j) {
        shortx8 bfr = *(const shortx8*)(Xw + (j * 16 + frow + kk) * 24 + d0);
#pragma unroll
        for (int i = 0; i < 4; ++i)
          acc[i][j] = __builtin_amdgcn_mfma_f32_16x16x32_bf16(
              afr[kt][i], bfr, acc[i][j], 0, 0, 0);
      }
    }

    int tok = tokbase + 2 * g + wc;
    __hip_bfloat16* hrow = h + (size_t)tok * NF;
#pragma unroll
    for (int i = 0; i < 4; ++i) {
#pragma unroll
      for (int r = 0; r < 4; ++r) {
        int ch = chb + wr * 64 + i * 16 + q * 4 + r;
        int w = 1 + (ch >= 32) + (ch >= 64) + (ch >= 128) + (ch >= 256) +
                (ch >= 512) + (ch >= 1024);
        int Tv = 51 - w;
        float v = -1e30f;
#pragma unroll
        for (int j = 0; j < NT; ++j) {
          int t = j * 16 + frow;
          if (t < Tv) v = fmaxf(v, acc[i][j][r]);
        }
        v = fmaxf(v, __shfl_xor(v, 1));
        v = fmaxf(v, __shfl_xor(v, 2));
        v = fmaxf(v, __shfl_xor(v, 4));
        v = fmaxf(v, __shfl_xor(v, 8));
        if (frow == 0)
          hrow[ch] = __float2bfloat16(fmaxf(v + bias[ch], 0.f));
      }
    }
    __syncthreads();
  }
}

__global__ __launch_bounds__(256) void conv_all(
    const int* __restrict__ chars, const __hip_bfloat16* __restrict__ embb,
    const __hip_bfloat16* __restrict__ Wb, const float* __restrict__ bias,
    __hip_bfloat16* __restrict__ h) {
  __shared__ __align__(16) __hip_bfloat16 Xs[2][2][72 * 24];
  int by = blockIdx.y;  // block-uniform dispatch, no divergence
  if (by == 0)
    conv_body<2, 4>(chars, embb, Wb, bias, h, 0, Xs);
  else if (by == 1)
    conv_body<2, 3>(chars, embb, Wb, bias, h, 128, Xs);
  else if (by < 8)
    conv_body<3, 3>(chars, embb, Wb, bias, h, 256 + (by - 2) * 128, Xs);
  else
    conv_body<4, 3>(chars, embb, Wb, bias, h, 1024 + (by - 8) * 128, Xs);
}

// ---------------------------------------------------------------------------
// Highway-fused GEMM: P[n,:] = h_src[n,:] @ W'^T (W' rows interleaved
// nl/gate). Epilogue pairs even/odd cols via shfl_xor(1), computes
// g = sigmoid(gate+b_g), h' = g*h + (1-g)*relu(nl+b_nl), writes Hdst.
// ---------------------------------------------------------------------------
__global__ __launch_bounds__(256) void gemm_hw(
    const __hip_bfloat16* __restrict__ A, const __hip_bfloat16* __restrict__ B,
    const float* __restrict__ hwb, __hip_bfloat16* __restrict__ Hdst) {
  const int K = KDIM;
  __shared__ __align__(16) __hip_bfloat16 As[128 * 32];
  __shared__ __align__(16) __hip_bfloat16 Bs[128 * 32];
  int tid = threadIdx.x;
  int wave = tid >> 6, lane = tid & 63;
  int wr = wave >> 1, wc = wave & 1;
  int bn = blockIdx.y, bm = blockIdx.x;

  int srow = lane >> 2;
  int skq  = (lane & 3) * 8;
  int frow = lane & 15;
  int fkq  = (lane >> 4) * 8;

  floatx4 acc[4][4];
  floatx4 zero = {0.f, 0.f, 0.f, 0.f};
#pragma unroll
  for (int i = 0; i < 4; ++i)
#pragma unroll
    for (int j = 0; j < 4; ++j) acc[i][j] = zero;

  const __hip_bfloat16* Ab = A + (size_t)bn * 128 * K;
  const __hip_bfloat16* Bb = B + (size_t)bm * 128 * K;

  for (int kb = 0; kb < K; kb += 32) {
    __syncthreads();
#pragma unroll
    for (int it = 0; it < 2; ++it) {
      int seg = wave * 2 + it;
      async_copy16(Ab + (size_t)(seg * 16 + srow) * K + kb + skq,
                   (char*)As + seg * 1024);
      async_copy16(Bb + (size_t)(seg * 16 + srow) * K + kb + skq,
                   (char*)Bs + seg * 1024);
    }
    __syncthreads();

    shortx8 af[4], bf[4];
#pragma unroll
    for (int i = 0; i < 4; ++i)
      af[i] = *(const shortx8*)(As + (wr * 64 + i * 16 + frow) * 32 + fkq);
#pragma unroll
    for (int j = 0; j < 4; ++j)
      bf[j] = *(const shortx8*)(Bs + (wc * 64 + j * 16 + frow) * 32 + fkq);
#pragma unroll
    for (int i = 0; i < 4; ++i)
#pragma unroll
      for (int j = 0; j < 4; ++j)
        acc[i][j] =
            __builtin_amdgcn_mfma_f32_16x16x32_bf16(af[i], bf[j], acc[i][j], 0, 0, 0);
  }

  int crow0 = bn * 128 + wr * 64 + (lane >> 4) * 4;
  int ccol0 = bm * 128 + wc * 64 + (lane & 15);
#pragma unroll
  for (int i = 0; i < 4; ++i)
#pragma unroll
    for (int j = 0; j < 4; ++j) {
      int gcol = ccol0 + j * 16;
      float bb = (gcol & 1) ? hwb[2048 + (gcol >> 1)] : hwb[gcol >> 1];
#pragma unroll
      for (int r = 0; r < 4; ++r) {
        int row = crow0 + i * 16 + r;
        float v = acc[i][j][r] + bb;
        float partner = __shfl_xor(v, 1);
        if (!(lane & 1)) {  // even lane holds nl, partner is gate pre-act
          float gte = 1.f / (1.f + expf(-partner));
          int ch = gcol >> 1;
          float hold = __bfloat162float(A[(size_t)row * 2048 + ch]);
          float hnew = gte * hold + (1.f - gte) * fmaxf(v, 0.f);
          Hdst[(size_t)row * 2048 + ch] = __float2bfloat16(hnew);
        }
      }
    }
}

// ---------------------------------------------------------------------------
// Plain GEMM for projection: C fp32 + bias.
// ---------------------------------------------------------------------------
__global__ __launch_bounds__(256) void gemm_proj(
    const __hip_bfloat16* __restrict__ A, const __hip_bfloat16* __restrict__ B,
    float* __restrict__ C, const float* __restrict__ bias, int M) {
  const int K = KDIM;
  __shared__ __align__(16) __hip_bfloat16 As[128 * 32];
  __shared__ __align__(16) __hip_bfloat16 Bs[128 * 32];
  int tid = threadIdx.x;
  int wave = tid >> 6, lane = tid & 63;
  int wr = wave >> 1, wc = wave & 1;
  int bn = blockIdx.y, bm = blockIdx.x;

  int srow = lane >> 2;
  int skq  = (lane & 3) * 8;
  int frow = lane & 15;
  int fkq  = (lane >> 4) * 8;

  floatx4 acc[4][4];
  floatx4 zero = {0.f, 0.f, 0.f, 0.f};
#pragma unroll
  for (int i = 0; i < 4; ++i)
#pragma unroll
    for (int j = 0; j < 4; ++j) acc[i][j] = zero;

  const __hip_bfloat16* Ab = A + (size_t)bn * 128 * K;
  const __hip_bfloat16* Bb = B + (size_t)bm * 128 * K;

  for (int kb = 0; kb < K; kb += 32) {
    __syncthreads();
#pragma unroll
    for (int it = 0; it < 2; ++it) {
      int seg = wave * 2 + it;
      async_copy16(Ab + (size_t)(seg * 16 + srow) * K + kb + skq,
                   (char*)As + seg * 1024);
      async_copy16(Bb + (size_t)(seg * 16 + srow) * K + kb + skq,
                   (char*)Bs + seg * 1024);
    }
    __syncthreads();

    shortx8 af[4], bf[4];
#pragma unroll
    for (int i = 0; i < 4; ++i)
      af[i] = *(const shortx8*)(As + (wr * 64 + i * 16 + frow) * 32 + fkq);
#pragma unroll
    for (int j = 0; j < 4; ++j)
      bf[j] = *(const shortx8*)(Bs + (wc * 64 + j * 16 + frow) * 32 + fkq);
#pragma unroll
    for (int i = 0; i < 4; ++i)
#pragma unroll
      for (int j = 0; j < 4; ++j)
        acc[i][j] =
            __builtin_amdgcn_mfma_f32_16x16x32_bf16(af[i], bf[j], acc[i][j], 0, 0, 0);
  }

  int crow0 = bn * 128 + wr * 64 + (lane >> 4) * 4;
  int ccol0 = bm * 128 + wc * 64 + (lane & 15);
#pragma unroll
  for (int i = 0; i < 4; ++i)
#pragma unroll
    for (int j = 0; j < 4; ++j) {
      int c = ccol0 + j * 16;
#pragma unroll
      for (int r = 0; r < 4; ++r) {
        int row = crow0 + i * 16 + r;
        C[(size_t)row * M + c] = acc[i][j][r] + bias[c];
      }
    }
}

// ---------------------------------------------------------------------------
extern "C" void kernel_launch(void* const* d_in, const int* in_sizes, int n_in,
                              void* d_out, int out_size, void* d_ws, size_t ws_size,
                              hipStream_t stream) {
  const int*   chars  = (const int*)d_in[1];
  const float* emb    = (const float*)d_in[2];
  const float* cw[7];
  const float* cb[7];
  for (int i = 0; i < 7; ++i) {
    cw[i] = (const float*)d_in[3 + 2 * i];
    cb[i] = (const float*)d_in[4 + 2 * i];
  }
  const float* hw_w0  = (const float*)d_in[17];
  const float* hw_b0  = (const float*)d_in[18];
  const float* hw_w1  = (const float*)d_in[19];
  const float* hw_b1  = (const float*)d_in[20];
  const float* proj_w = (const float*)d_in[21];
  const float* proj_b = (const float*)d_in[22];
  float* out = (float*)d_out;

  // Workspace (82 MiB):
  //   [0,16)   h   bf16 4096x2048      [16,32) h2  bf16 4096x2048
  //   [32,48)  convWb 512KB + convBc 8KB + embb 8.4KB
  //   [48,64)  w0b  [64,80) w1b  [80,82) pwb
  char* ws = (char*)d_ws;
  __hip_bfloat16* h      = (__hip_bfloat16*)(ws);
  __hip_bfloat16* h2     = (__hip_bfloat16*)(ws + (16ull << 20));
  __hip_bfloat16* convWb = (__hip_bfloat16*)(ws + (32ull << 20));
  float*          convBc = (float*)(ws + (32ull << 20) + 524288);
  __hip_bfloat16* embb   = (__hip_bfloat16*)(ws + (32ull << 20) + 524288 + 8192);
  __hip_bfloat16* w0b    = (__hip_bfloat16*)(ws + (48ull << 20));
  __hip_bfloat16* w1b    = (__hip_bfloat16*)(ws + (64ull << 20));
  __hip_bfloat16* pwb    = (__hip_bfloat16*)(ws + (80ull << 20));

  cvt_hw<<<(HID * KDIM) / 256, 256, 0, stream>>>(hw_w0, w0b);
  cvt_hw<<<(HID * KDIM) / 256, 256, 0, stream>>>(hw_w1, w1b);
  cvt_kernel<<<(PDIM * KDIM) / 256, 256, 0, stream>>>(proj_w, pwb, PDIM * KDIM);
  conv_wprep<<<(262144 + 2048 + 4192 + 255) / 256, 256, 0, stream>>>(
      cw[0], cw[1], cw[2], cw[3], cw[4], cw[5], cw[6],
      cb[0], cb[1], cb[2], cb[3], cb[4], cb[5], cb[6], emb,
      convWb, convBc, embb);

  conv_all<<<dim3(NTOK / 32, 16), 256, 0, stream>>>(chars, embb, convWb,
                                                    convBc, h);

  gemm_hw<<<dim3(HID / 128, NTOK / 128), 256, 0, stream>>>(h, w0b, hw_b0, h2);
  gemm_hw<<<dim3(HID / 128, NTOK / 128), 256, 0, stream>>>(h2, w1b, hw_b1, h);
  gemm_proj<<<dim3(PDIM / 128, NTOK / 128), 256, 0, stream>>>(h, pwb, out,
                                                              proj_b, PDIM);
}

// Round 5
// 536.515 us; speedup vs baseline: 2.5518x; 1.3737x over previous
//
#include <hip/hip_runtime.h>
#include <hip/hip_bf16.h>

// ---------------------------------------------------------------------------
// ConvTokenEmbedder: char-CNN -> 2x highway -> projection
// R5: conv MFMA transposed: A=X (rows=t), B=W (cols=ch, register-resident).
//     Max-over-t = register fmax + 2 shfl per 16-ch tile (was 4 shfl/ch);
//     coalesced 1-store-per-lane epilogue via cndmask select. 4 tokens/group
//     (1/wave), 8 barriers/block. chars preloaded to LDS once per block.
//     Zero-init via shared zero C operand on kt=0. 64-ch y-blocks.
// ---------------------------------------------------------------------------

#define NTOK 4096
#define NF   2048
#define KDIM 2048
#define HID  4096
#define PDIM 512

typedef __attribute__((ext_vector_type(4))) float floatx4;
typedef __attribute__((ext_vector_type(8))) short shortx8;

__device__ inline void async_copy16(const void* g, void* l) {
  __builtin_amdgcn_global_load_lds(
      (const __attribute__((address_space(1))) void*)(uintptr_t)g,
      (__attribute__((address_space(3))) void*)(uint32_t)(uintptr_t)l,
      16, 0, 0);
}

// ---------------------------------------------------------------------------
__global__ __launch_bounds__(256) void cvt_kernel(
    const float* __restrict__ s, __hip_bfloat16* __restrict__ d, int n) {
  int i = blockIdx.x * 256 + threadIdx.x;
  if (i < n) d[i] = __float2bfloat16(s[i]);
}

// Highway weight cvt with nl/gate row interleave: dst row r = src row
// (r>>1) + (r&1)*2048. So cols 2j/2j+1 of p' are (nl_j, gate_j).
__global__ __launch_bounds__(256) void cvt_hw(
    const float* __restrict__ s, __hip_bfloat16* __restrict__ d) {
  int i = blockIdx.x * 256 + threadIdx.x;  // over 4096*2048
  int r = i >> 11, k = i & 2047;
  int sr = (r >> 1) + (r & 1) * 2048;
  d[i] = __float2bfloat16(s[(size_t)sr * 2048 + k]);
}

// ---------------------------------------------------------------------------
// Conv weight prep: Wb[ch][kp], kp = k*16+d, K padded to 128 (zeros k>=w).
// Plus bias pack [2048] and bf16 emb table [262*16].
// ---------------------------------------------------------------------------
__global__ __launch_bounds__(256) void conv_wprep(
    const float* __restrict__ w0, const float* __restrict__ w1,
    const float* __restrict__ w2, const float* __restrict__ w3,
    const float* __restrict__ w4, const float* __restrict__ w5,
    const float* __restrict__ w6,
    const float* __restrict__ b0, const float* __restrict__ b1,
    const float* __restrict__ b2, const float* __restrict__ b3,
    const float* __restrict__ b4, const float* __restrict__ b5,
    const float* __restrict__ b6, const float* __restrict__ emb,
    __hip_bfloat16* __restrict__ Wb, float* __restrict__ Bc,
    __hip_bfloat16* __restrict__ embb) {
  int idx = blockIdx.x * 256 + threadIdx.x;
  const int start[7] = {0, 32, 64, 128, 256, 512, 1024};
  const float* ws[7] = {w0, w1, w2, w3, w4, w5, w6};
  const float* bs[7] = {b0, b1, b2, b3, b4, b5, b6};
  if (idx < 262144) {
    int ch = idx >> 7, kp = idx & 127;
    int f = (ch >= 32) + (ch >= 64) + (ch >= 128) + (ch >= 256) +
            (ch >= 512) + (ch >= 1024);
    int w = f + 1, lc = ch - start[f];
    int d = kp & 15, k = kp >> 4;
    float v = (k < w) ? ws[f][((size_t)lc * 16 + d) * w + k] : 0.f;
    Wb[idx] = __float2bfloat16(v);
  } else if (idx < 262144 + 2048) {
    int ch = idx - 262144;
    int f = (ch >= 32) + (ch >= 64) + (ch >= 128) + (ch >= 256) +
            (ch >= 512) + (ch >= 1024);
    Bc[ch] = bs[f][ch - start[f]];
  } else if (idx < 262144 + 2048 + 4192) {
    int e = idx - 262144 - 2048;
    embb[e] = __float2bfloat16(emb[e]);
  }
}

// ---------------------------------------------------------------------------
// Conv body. Block: 64 channels (chb) x 32 tokens; 8 groups of 4 tokens
// (one token per wave). A = X window tile (rows=t, sliding over LDS E),
// B = W register-resident (4 ch-tiles x NKT shortx8). C: col=ch, rows=t.
// Epilogue: per ch-tile register max over (i,r), shfl_xor 16/32, cndmask
// select -> one coalesced 128B bf16 store per wave per group.
// ---------------------------------------------------------------------------
template <int NKT, int NT>
__device__ __forceinline__ void conv_body(
    const __hip_bfloat16* __restrict__ embb,
    const __hip_bfloat16* __restrict__ Wb, const float* __restrict__ bias,
    __hip_bfloat16* __restrict__ h, int chb,
    __hip_bfloat16 (*Xs)[4][72 * 24], int* cidx) {
  int tid = threadIdx.x, wave = tid >> 6, lane = tid & 63;
  int frow = lane & 15, q = lane >> 4;
  int tokbase = blockIdx.x * 32;

  // W fragments (B operand): B[n=frow=ch][k=q*8+jj], register-resident.
  shortx8 wreg[NKT][4];
#pragma unroll
  for (int kt = 0; kt < NKT; ++kt)
#pragma unroll
    for (int j = 0; j < 4; ++j)
      wreg[kt][j] = *(const shortx8*)(
          Wb + (size_t)(chb + j * 16 + frow) * 128 + kt * 32 + q * 8);

  // Per-lane bias (ch = chb + lane) and per-(j,lane) valid-T bound.
  float blane = bias[chb + lane];
  int Tvj[4];
#pragma unroll
  for (int j = 0; j < 4; ++j) {
    int ch = chb + j * 16 + frow;
    int w = 1 + (ch >= 32) + (ch >= 64) + (ch >= 128) + (ch >= 256) +
            (ch >= 512) + (ch >= 1024);
    Tvj[j] = 51 - w;
  }

  // Stage helper: 4 tokens x 72 rows (rows >= 50 zero; only written while
  // both buffers are first populated, g<=1).
  auto stage = [&](int g, int buf) {
#pragma unroll
    for (int rep = 0; rep < 2; ++rep) {
      int rr = tid + rep * 256;
      if (rr < 288) {
        int tk = rr / 72, r = rr - tk * 72;
        if (r < 50) {
          int c = cidx[(g * 4 + tk) * 50 + r];
          const shortx8* e = (const shortx8*)(embb + c * 16);
          *(shortx8*)(&Xs[buf][tk][r * 24]) = e[0];
          *(shortx8*)(&Xs[buf][tk][r * 24 + 8]) = e[1];
        } else if (g <= 1) {
          shortx8 z = {0, 0, 0, 0, 0, 0, 0, 0};
          *(shortx8*)(&Xs[buf][tk][r * 24]) = z;
          *(shortx8*)(&Xs[buf][tk][r * 24 + 8]) = z;
        }
      }
    }
  };

  stage(0, 0);
  __syncthreads();

  const floatx4 zero = {0.f, 0.f, 0.f, 0.f};
#pragma unroll 1
  for (int g = 0; g < 8; ++g) {
    if (g < 7) stage(g + 1, (g + 1) & 1);

    const __hip_bfloat16* Xw = &Xs[g & 1][wave][0];
    floatx4 acc[NT][4];

#pragma unroll
    for (int kt = 0; kt < NKT; ++kt) {
      int kk = kt * 2 + (q >> 1);
      int d0 = (q & 1) * 8;
      shortx8 xf[NT];
#pragma unroll
      for (int i = 0; i < NT; ++i)
        xf[i] = *(const shortx8*)(Xw + (i * 16 + frow + kk) * 24 + d0);
#pragma unroll
      for (int i = 0; i < NT; ++i)
#pragma unroll
        for (int j = 0; j < 4; ++j) {
          if (kt == 0)
            acc[i][j] = __builtin_amdgcn_mfma_f32_16x16x32_bf16(
                xf[i], wreg[0][j], zero, 0, 0, 0);
          else
            acc[i][j] = __builtin_amdgcn_mfma_f32_16x16x32_bf16(
                xf[i], wreg[kt][j], acc[i][j], 0, 0, 0);
        }
    }

    // Epilogue: max over t (rows), 2 shuffles, select, coalesced store.
    float vj[4];
#pragma unroll
    for (int j = 0; j < 4; ++j) {
      float v = -1e30f;
#pragma unroll
      for (int i = 0; i < NT; ++i) {
#pragma unroll
        for (int r = 0; r < 4; ++r) {
          if (i < 2) {  // t <= 31 < Tv_min=44: always valid
            v = fmaxf(v, acc[i][j][r]);
          } else {
            int t = i * 16 + q * 4 + r;
            if (t < Tvj[j]) v = fmaxf(v, acc[i][j][r]);
          }
        }
      }
      v = fmaxf(v, __shfl_xor(v, 16));
      v = fmaxf(v, __shfl_xor(v, 32));
      vj[j] = v;
    }
    float r0 = (q & 2) ? vj[2] : vj[0];
    float r1 = (q & 2) ? vj[3] : vj[1];
    float rv = (q & 1) ? r1 : r0;
    int tok = tokbase + g * 4 + wave;
    h[(size_t)tok * NF + chb + lane] =
        __float2bfloat16(fmaxf(rv + blane, 0.f));
    __syncthreads();
  }
}

__global__ __launch_bounds__(256) void conv_all(
    const int* __restrict__ chars, const __hip_bfloat16* __restrict__ embb,
    const __hip_bfloat16* __restrict__ Wb, const float* __restrict__ bias,
    __hip_bfloat16* __restrict__ h) {
  __shared__ __align__(16) __hip_bfloat16 Xs[2][4][72 * 24];
  __shared__ __align__(16) int cidx[32 * 50];
  int tid = threadIdx.x;
  // Preload all 32 tokens' char indices (6400B contiguous).
  for (int c = tid; c < 400; c += 256) {
    int4 v = *(const int4*)(chars + (size_t)blockIdx.x * 1600 + c * 4);
    *(int4*)(cidx + c * 4) = v;
  }
  __syncthreads();

  int by = blockIdx.y;  // block-uniform dispatch, no divergence
  if (by == 0)
    conv_body<1, 4>(embb, Wb, bias, h, 0, Xs, cidx);          // w1,w2
  else if (by < 4)
    conv_body<2, 3>(embb, Wb, bias, h, 64 + (by - 1) * 64, Xs, cidx);   // w3,w4
  else if (by < 16)
    conv_body<3, 3>(embb, Wb, bias, h, 256 + (by - 4) * 64, Xs, cidx);  // w5,w6
  else
    conv_body<4, 3>(embb, Wb, bias, h, 1024 + (by - 16) * 64, Xs, cidx); // w7
}

// ---------------------------------------------------------------------------
// Highway-fused GEMM: P[n,:] = h_src[n,:] @ W'^T (W' rows interleaved
// nl/gate). Epilogue pairs even/odd cols via shfl_xor(1), computes
// g = sigmoid(gate+b_g), h' = g*h + (1-g)*relu(nl+b_nl), writes Hdst.
// ---------------------------------------------------------------------------
__global__ __launch_bounds__(256) void gemm_hw(
    const __hip_bfloat16* __restrict__ A, const __hip_bfloat16* __restrict__ B,
    const float* __restrict__ hwb, __hip_bfloat16* __restrict__ Hdst) {
  const int K = KDIM;
  __shared__ __align__(16) __hip_bfloat16 As[128 * 32];
  __shared__ __align__(16) __hip_bfloat16 Bs[128 * 32];
  int tid = threadIdx.x;
  int wave = tid >> 6, lane = tid & 63;
  int wr = wave >> 1, wc = wave & 1;
  int bn = blockIdx.y, bm = blockIdx.x;

  int srow = lane >> 2;
  int skq  = (lane & 3) * 8;
  int frow = lane & 15;
  int fkq  = (lane >> 4) * 8;

  floatx4 acc[4][4];
  floatx4 zero = {0.f, 0.f, 0.f, 0.f};
#pragma unroll
  for (int i = 0; i < 4; ++i)
#pragma unroll
    for (int j = 0; j < 4; ++j) acc[i][j] = zero;

  const __hip_bfloat16* Ab = A + (size_t)bn * 128 * K;
  const __hip_bfloat16* Bb = B + (size_t)bm * 128 * K;

  for (int kb = 0; kb < K; kb += 32) {
    __syncthreads();
#pragma unroll
    for (int it = 0; it < 2; ++it) {
      int seg = wave * 2 + it;
      async_copy16(Ab + (size_t)(seg * 16 + srow) * K + kb + skq,
                   (char*)As + seg * 1024);
      async_copy16(Bb + (size_t)(seg * 16 + srow) * K + kb + skq,
                   (char*)Bs + seg * 1024);
    }
    __syncthreads();

    shortx8 af[4], bf[4];
#pragma unroll
    for (int i = 0; i < 4; ++i)
      af[i] = *(const shortx8*)(As + (wr * 64 + i * 16 + frow) * 32 + fkq);
#pragma unroll
    for (int j = 0; j < 4; ++j)
      bf[j] = *(const shortx8*)(Bs + (wc * 64 + j * 16 + frow) * 32 + fkq);
#pragma unroll
    for (int i = 0; i < 4; ++i)
#pragma unroll
      for (int j = 0; j < 4; ++j)
        acc[i][j] =
            __builtin_amdgcn_mfma_f32_16x16x32_bf16(af[i], bf[j], acc[i][j], 0, 0, 0);
  }

  int crow0 = bn * 128 + wr * 64 + (lane >> 4) * 4;
  int ccol0 = bm * 128 + wc * 64 + (lane & 15);
#pragma unroll
  for (int i = 0; i < 4; ++i)
#pragma unroll
    for (int j = 0; j < 4; ++j) {
      int gcol = ccol0 + j * 16;
      float bb = (gcol & 1) ? hwb[2048 + (gcol >> 1)] : hwb[gcol >> 1];
#pragma unroll
      for (int r = 0; r < 4; ++r) {
        int row = crow0 + i * 16 + r;
        float v = acc[i][j][r] + bb;
        float partner = __shfl_xor(v, 1);
        if (!(lane & 1)) {  // even lane holds nl, partner is gate pre-act
          float gte = 1.f / (1.f + expf(-partner));
          int ch = gcol >> 1;
          float hold = __bfloat162float(A[(size_t)row * 2048 + ch]);
          float hnew = gte * hold + (1.f - gte) * fmaxf(v, 0.f);
          Hdst[(size_t)row * 2048 + ch] = __float2bfloat16(hnew);
        }
      }
    }
}

// ---------------------------------------------------------------------------
// Plain GEMM for projection: C fp32 + bias.
// ---------------------------------------------------------------------------
__global__ __launch_bounds__(256) void gemm_proj(
    const __hip_bfloat16* __restrict__ A, const __hip_bfloat16* __restrict__ B,
    float* __restrict__ C, const float* __restrict__ bias, int M) {
  const int K = KDIM;
  __shared__ __align__(16) __hip_bfloat16 As[128 * 32];
  __shared__ __align__(16) __hip_bfloat16 Bs[128 * 32];
  int tid = threadIdx.x;
  int wave = tid >> 6, lane = tid & 63;
  int wr = wave >> 1, wc = wave & 1;
  int bn = blockIdx.y, bm = blockIdx.x;

  int srow = lane >> 2;
  int skq  = (lane & 3) * 8;
  int frow = lane & 15;
  int fkq  = (lane >> 4) * 8;

  floatx4 acc[4][4];
  floatx4 zero = {0.f, 0.f, 0.f, 0.f};
#pragma unroll
  for (int i = 0; i < 4; ++i)
#pragma unroll
    for (int j = 0; j < 4; ++j) acc[i][j] = zero;

  const __hip_bfloat16* Ab = A + (size_t)bn * 128 * K;
  const __hip_bfloat16* Bb = B + (size_t)bm * 128 * K;

  for (int kb = 0; kb < K; kb += 32) {
    __syncthreads();
#pragma unroll
    for (int it = 0; it < 2; ++it) {
      int seg = wave * 2 + it;
      async_copy16(Ab + (size_t)(seg * 16 + srow) * K + kb + skq,
                   (char*)As + seg * 1024);
      async_copy16(Bb + (size_t)(seg * 16 + srow) * K + kb + skq,
                   (char*)Bs + seg * 1024);
    }
    __syncthreads();

    shortx8 af[4], bf[4];
#pragma unroll
    for (int i = 0; i < 4; ++i)
      af[i] = *(const shortx8*)(As + (wr * 64 + i * 16 + frow) * 32 + fkq);
#pragma unroll
    for (int j = 0; j < 4; ++j)
      bf[j] = *(const shortx8*)(Bs + (wc * 64 + j * 16 + frow) * 32 + fkq);
#pragma unroll
    for (int i = 0; i < 4; ++i)
#pragma unroll
      for (int j = 0; j < 4; ++j)
        acc[i][j] =
            __builtin_amdgcn_mfma_f32_16x16x32_bf16(af[i], bf[j], acc[i][j], 0, 0, 0);
  }

  int crow0 = bn * 128 + wr * 64 + (lane >> 4) * 4;
  int ccol0 = bm * 128 + wc * 64 + (lane & 15);
#pragma unroll
  for (int i = 0; i < 4; ++i)
#pragma unroll
    for (int j = 0; j < 4; ++j) {
      int c = ccol0 + j * 16;
#pragma unroll
      for (int r = 0; r < 4; ++r) {
        int row = crow0 + i * 16 + r;
        C[(size_t)row * M + c] = acc[i][j][r] + bias[c];
      }
    }
}

// ---------------------------------------------------------------------------
extern "C" void kernel_launch(void* const* d_in, const int* in_sizes, int n_in,
                              void* d_out, int out_size, void* d_ws, size_t ws_size,
                              hipStream_t stream) {
  const int*   chars  = (const int*)d_in[1];
  const float* emb    = (const float*)d_in[2];
  const float* cw[7];
  const float* cb[7];
  for (int i = 0; i < 7; ++i) {
    cw[i] = (const float*)d_in[3 + 2 * i];
    cb[i] = (const float*)d_in[4 + 2 * i];
  }
  const float* hw_w0  = (const float*)d_in[17];
  const float* hw_b0  = (const float*)d_in[18];
  const float* hw_w1  = (const float*)d_in[19];
  const float* hw_b1  = (const float*)d_in[20];
  const float* proj_w = (const float*)d_in[21];
  const float* proj_b = (const float*)d_in[22];
  float* out = (float*)d_out;

  // Workspace (82 MiB):
  //   [0,16)   h   bf16 4096x2048      [16,32) h2  bf16 4096x2048
  //   [32,48)  convWb 512KB + convBc 8KB + embb 8.4KB
  //   [48,64)  w0b  [64,80) w1b  [80,82) pwb
  char* ws = (char*)d_ws;
  __hip_bfloat16* h      = (__hip_bfloat16*)(ws);
  __hip_bfloat16* h2     = (__hip_bfloat16*)(ws + (16ull << 20));
  __hip_bfloat16* convWb = (__hip_bfloat16*)(ws + (32ull << 20));
  float*          convBc = (float*)(ws + (32ull << 20) + 524288);
  __hip_bfloat16* embb   = (__hip_bfloat16*)(ws + (32ull << 20) + 524288 + 8192);
  __hip_bfloat16* w0b    = (__hip_bfloat16*)(ws + (48ull << 20));
  __hip_bfloat16* w1b    = (__hip_bfloat16*)(ws + (64ull << 20));
  __hip_bfloat16* pwb    = (__hip_bfloat16*)(ws + (80ull << 20));

  cvt_hw<<<(HID * KDIM) / 256, 256, 0, stream>>>(hw_w0, w0b);
  cvt_hw<<<(HID * KDIM) / 256, 256, 0, stream>>>(hw_w1, w1b);
  cvt_kernel<<<(PDIM * KDIM) / 256, 256, 0, stream>>>(proj_w, pwb, PDIM * KDIM);
  conv_wprep<<<(262144 + 2048 + 4192 + 255) / 256, 256, 0, stream>>>(
      cw[0], cw[1], cw[2], cw[3], cw[4], cw[5], cw[6],
      cb[0], cb[1], cb[2], cb[3], cb[4], cb[5], cb[6], emb,
      convWb, convBc, embb);

  conv_all<<<dim3(NTOK / 32, 32), 256, 0, stream>>>(chars, embb, convWb,
                                                    convBc, h);

  gemm_hw<<<dim3(HID / 128, NTOK / 128), 256, 0, stream>>>(h, w0b, hw_b0, h2);
  gemm_hw<<<dim3(HID / 128, NTOK / 128), 256, 0, stream>>>(h2, w1b, hw_b1, h);
  gemm_proj<<<dim3(PDIM / 128, NTOK / 128), 256, 0, stream>>>(h, pwb, out,
                                                              proj_b, PDIM);
}

// Round 7
// 520.394 us; speedup vs baseline: 2.6308x; 1.0310x over previous
//
#include <hip/hip_runtime.h>
#include <hip/hip_bf16.h>

// ---------------------------------------------------------------------------
// ConvTokenEmbedder: char-CNN -> 2x highway -> projection
// R7 = R6 with the staging-stride bug fixed: each global_load_lds wave-call
//     stages 64 lanes x 16B = 1024B, so segment stride is 1024 (was 2048 ->
//     As overran into Bs -> NaN).
// GEMMs: BK=64 + XOR chunk-swizzle (source-side) -> frag ds_read_b128 2-way.
// Conv: 4 uniform template launches, W register-resident, X double-buffered.
// ---------------------------------------------------------------------------

#define NTOK 4096
#define NF   2048
#define KDIM 2048
#define HID  4096
#define PDIM 512

typedef __attribute__((ext_vector_type(4))) float floatx4;
typedef __attribute__((ext_vector_type(8))) short shortx8;

__device__ inline void async_copy16(const void* g, void* l) {
  __builtin_amdgcn_global_load_lds(
      (const __attribute__((address_space(1))) void*)(uintptr_t)g,
      (__attribute__((address_space(3))) void*)(uint32_t)(uintptr_t)l,
      16, 0, 0);
}

// ---------------------------------------------------------------------------
__global__ __launch_bounds__(256) void cvt_kernel(
    const float* __restrict__ s, __hip_bfloat16* __restrict__ d, int n) {
  int i = blockIdx.x * 256 + threadIdx.x;
  if (i < n) d[i] = __float2bfloat16(s[i]);
}

// Highway weight cvt with nl/gate row interleave: dst row r = src row
// (r>>1) + (r&1)*2048. So cols 2j/2j+1 of p' are (nl_j, gate_j).
__global__ __launch_bounds__(256) void cvt_hw(
    const float* __restrict__ s, __hip_bfloat16* __restrict__ d) {
  int i = blockIdx.x * 256 + threadIdx.x;  // over 4096*2048
  int r = i >> 11, k = i & 2047;
  int sr = (r >> 1) + (r & 1) * 2048;
  d[i] = __float2bfloat16(s[(size_t)sr * 2048 + k]);
}

// ---------------------------------------------------------------------------
// Conv weight prep: Wb[ch][kp], kp = k*16+d, K padded to 128 (zeros k>=w).
// Plus bias pack [2048] and bf16 emb table [262*16].
// ---------------------------------------------------------------------------
__global__ __launch_bounds__(256) void conv_wprep(
    const float* __restrict__ w0, const float* __restrict__ w1,
    const float* __restrict__ w2, const float* __restrict__ w3,
    const float* __restrict__ w4, const float* __restrict__ w5,
    const float* __restrict__ w6,
    const float* __restrict__ b0, const float* __restrict__ b1,
    const float* __restrict__ b2, const float* __restrict__ b3,
    const float* __restrict__ b4, const float* __restrict__ b5,
    const float* __restrict__ b6, const float* __restrict__ emb,
    __hip_bfloat16* __restrict__ Wb, float* __restrict__ Bc,
    __hip_bfloat16* __restrict__ embb) {
  int idx = blockIdx.x * 256 + threadIdx.x;
  const int start[7] = {0, 32, 64, 128, 256, 512, 1024};
  const float* ws[7] = {w0, w1, w2, w3, w4, w5, w6};
  const float* bs[7] = {b0, b1, b2, b3, b4, b5, b6};
  if (idx < 262144) {
    int ch = idx >> 7, kp = idx & 127;
    int f = (ch >= 32) + (ch >= 64) + (ch >= 128) + (ch >= 256) +
            (ch >= 512) + (ch >= 1024);
    int w = f + 1, lc = ch - start[f];
    int d = kp & 15, k = kp >> 4;
    float v = (k < w) ? ws[f][((size_t)lc * 16 + d) * w + k] : 0.f;
    Wb[idx] = __float2bfloat16(v);
  } else if (idx < 262144 + 2048) {
    int ch = idx - 262144;
    int f = (ch >= 32) + (ch >= 64) + (ch >= 128) + (ch >= 256) +
            (ch >= 512) + (ch >= 1024);
    Bc[ch] = bs[f][ch - start[f]];
  } else if (idx < 262144 + 2048 + 4192) {
    int e = idx - 262144 - 2048;
    embb[e] = __float2bfloat16(emb[e]);
  }
}

// ---------------------------------------------------------------------------
// Conv kernel (one template instantiation per width class -> uniform LDS).
// Block: 64 channels x 32 tokens; 8 groups of 4 tokens (one per wave).
// A = X window tile (rows=t, stride 24: bank-stride 12 -> 2-way only),
// B = W register-resident. Epilogue: register max over t, shfl 16/32,
// cndmask select, one coalesced 128B store per wave per group.
// ---------------------------------------------------------------------------
template <int NKT, int NT, int ROWS>
__global__ __launch_bounds__(256) void conv_k(
    const int* __restrict__ chars, const __hip_bfloat16* __restrict__ embb,
    const __hip_bfloat16* __restrict__ Wb, const float* __restrict__ bias,
    __hip_bfloat16* __restrict__ h, int chbase) {
  __shared__ __align__(16) __hip_bfloat16 Xs[2 * 4 * ROWS * 24];
  int tid = threadIdx.x, wave = tid >> 6, lane = tid & 63;
  int frow = lane & 15, q = lane >> 4;
  int chb = chbase + blockIdx.y * 64;
  int tokbase = blockIdx.x * 32;

  // W fragments (B operand): B[n=frow=ch][k=q*8+jj], register-resident.
  shortx8 wreg[NKT][4];
#pragma unroll
  for (int kt = 0; kt < NKT; ++kt)
#pragma unroll
    for (int j = 0; j < 4; ++j)
      wreg[kt][j] = *(const shortx8*)(
          Wb + (size_t)(chb + j * 16 + frow) * 128 + kt * 32 + q * 8);

  float blane = bias[chb + lane];
  int Tvj[4];
#pragma unroll
  for (int j = 0; j < 4; ++j) {
    int ch = chb + j * 16 + frow;
    int w = 1 + (ch >= 32) + (ch >= 64) + (ch >= 128) + (ch >= 256) +
            (ch >= 512) + (ch >= 1024);
    Tvj[j] = 51 - w;
  }

  auto stage = [&](int g, int buf) {
    constexpr int NST = 4 * ROWS;
#pragma unroll
    for (int rep = 0; rep < (NST + 255) / 256; ++rep) {
      int rr = tid + rep * 256;
      if (rr < NST) {
        int tk = rr / ROWS, r = rr - tk * ROWS;
        __hip_bfloat16* dst = Xs + ((size_t)(buf * 4 + tk) * ROWS + r) * 24;
        if (r < 50) {
          int c = chars[(size_t)(tokbase + g * 4 + tk) * 50 + r];
          const shortx8* e = (const shortx8*)(embb + c * 16);
          *(shortx8*)(dst) = e[0];
          *(shortx8*)(dst + 8) = e[1];
        } else if (g <= 1) {
          shortx8 z = {0, 0, 0, 0, 0, 0, 0, 0};
          *(shortx8*)(dst) = z;
          *(shortx8*)(dst + 8) = z;
        }
      }
    }
  };

  stage(0, 0);
  __syncthreads();

  const floatx4 zero = {0.f, 0.f, 0.f, 0.f};
#pragma unroll 1
  for (int g = 0; g < 8; ++g) {
    if (g < 7) stage(g + 1, (g + 1) & 1);

    const __hip_bfloat16* Xw = Xs + (size_t)((g & 1) * 4 + wave) * ROWS * 24;
    floatx4 acc[NT][4];

#pragma unroll
    for (int kt = 0; kt < NKT; ++kt) {
      int kk = kt * 2 + (q >> 1);
      int d0 = (q & 1) * 8;
      shortx8 xf[NT];
#pragma unroll
      for (int i = 0; i < NT; ++i)
        xf[i] = *(const shortx8*)(Xw + (i * 16 + frow + kk) * 24 + d0);
#pragma unroll
      for (int i = 0; i < NT; ++i)
#pragma unroll
        for (int j = 0; j < 4; ++j) {
          if (kt == 0)
            acc[i][j] = __builtin_amdgcn_mfma_f32_16x16x32_bf16(
                xf[i], wreg[0][j], zero, 0, 0, 0);
          else
            acc[i][j] = __builtin_amdgcn_mfma_f32_16x16x32_bf16(
                xf[i], wreg[kt][j], acc[i][j], 0, 0, 0);
        }
    }

    float vj[4];
#pragma unroll
    for (int j = 0; j < 4; ++j) {
      float v = -1e30f;
#pragma unroll
      for (int i = 0; i < NT; ++i) {
#pragma unroll
        for (int r = 0; r < 4; ++r) {
          if (i < 2) {  // t <= 31 < Tv_min=44: always valid
            v = fmaxf(v, acc[i][j][r]);
          } else {
            int t = i * 16 + q * 4 + r;
            if (t < Tvj[j]) v = fmaxf(v, acc[i][j][r]);
          }
        }
      }
      v = fmaxf(v, __shfl_xor(v, 16));
      v = fmaxf(v, __shfl_xor(v, 32));
      vj[j] = v;
    }
    float r0 = (q & 2) ? vj[2] : vj[0];
    float r1 = (q & 2) ? vj[3] : vj[1];
    float rv = (q & 1) ? r1 : r0;
    int tok = tokbase + g * 4 + wave;
    h[(size_t)tok * NF + chb + lane] =
        __float2bfloat16(fmaxf(rv + blane, 0.f));
    __syncthreads();
  }
}

// ---------------------------------------------------------------------------
// Highway-fused GEMM, BK=64, XOR-swizzled staging. 128x128 tile.
// LDS row stride 64 elems (128 B). Seg = 8 rows = 64 lanes x 16B = 1024B.
// Slot c of row r holds global chunk c^(r&7); frag read of chunk k uses
// slot k^(r&7) -> over 16 frow lanes slots sweep all 8 bank groups (2-way).
// Epilogue: pairs even/odd cols via shfl_xor(1), g=sigmoid(gate+b),
// h' = g*h + (1-g)*relu(nl+b), writes Hdst.
// ---------------------------------------------------------------------------
__global__ __launch_bounds__(256) void gemm_hw(
    const __hip_bfloat16* __restrict__ A, const __hip_bfloat16* __restrict__ B,
    const float* __restrict__ hwb, __hip_bfloat16* __restrict__ Hdst) {
  const int K = KDIM;
  __shared__ __align__(16) __hip_bfloat16 As[128 * 64];
  __shared__ __align__(16) __hip_bfloat16 Bs[128 * 64];
  int tid = threadIdx.x;
  int wave = tid >> 6, lane = tid & 63;
  int wr = wave >> 1, wc = wave & 1;
  int bn = blockIdx.y, bm = blockIdx.x;

  int sr8 = lane >> 3;       // staging: row within 8-row segment
  int sc8 = lane & 7;        // staging: 16B chunk slot
  int frow = lane & 15;
  int q    = lane >> 4;

  floatx4 acc[4][4];
  floatx4 zero = {0.f, 0.f, 0.f, 0.f};
#pragma unroll
  for (int i = 0; i < 4; ++i)
#pragma unroll
    for (int j = 0; j < 4; ++j) acc[i][j] = zero;

  const __hip_bfloat16* Ab = A + (size_t)bn * 128 * K;
  const __hip_bfloat16* Bb = B + (size_t)bm * 128 * K;

  for (int kb = 0; kb < K; kb += 64) {
    __syncthreads();
#pragma unroll
    for (int it = 0; it < 4; ++it) {
      int seg = wave * 4 + it;          // 16 segs x 8 rows
      int r = seg * 8 + sr8;
      int gc = sc8 ^ (r & 7);           // source chunk swizzle
      async_copy16(Ab + (size_t)r * K + kb + gc * 8, (char*)As + seg * 1024);
      async_copy16(Bb + (size_t)r * K + kb + gc * 8, (char*)Bs + seg * 1024);
    }
    __syncthreads();

#pragma unroll
    for (int s = 0; s < 2; ++s) {
      shortx8 af[4], bf[4];
#pragma unroll
      for (int i = 0; i < 4; ++i) {
        int r = wr * 64 + i * 16 + frow;
        af[i] = *(const shortx8*)(As + r * 64 + ((s * 4 + q) ^ (r & 7)) * 8);
      }
#pragma unroll
      for (int j = 0; j < 4; ++j) {
        int r = wc * 64 + j * 16 + frow;
        bf[j] = *(const shortx8*)(Bs + r * 64 + ((s * 4 + q) ^ (r & 7)) * 8);
      }
#pragma unroll
      for (int i = 0; i < 4; ++i)
#pragma unroll
        for (int j = 0; j < 4; ++j)
          acc[i][j] = __builtin_amdgcn_mfma_f32_16x16x32_bf16(
              af[i], bf[j], acc[i][j], 0, 0, 0);
    }
  }

  int crow0 = bn * 128 + wr * 64 + q * 4;
  int ccol0 = bm * 128 + wc * 64 + frow;
#pragma unroll
  for (int i = 0; i < 4; ++i)
#pragma unroll
    for (int j = 0; j < 4; ++j) {
      int gcol = ccol0 + j * 16;
      float bb = (gcol & 1) ? hwb[2048 + (gcol >> 1)] : hwb[gcol >> 1];
#pragma unroll
      for (int r = 0; r < 4; ++r) {
        int row = crow0 + i * 16 + r;
        float v = acc[i][j][r] + bb;
        float partner = __shfl_xor(v, 1);
        if (!(lane & 1)) {  // even lane holds nl, partner is gate pre-act
          float gte = 1.f / (1.f + expf(-partner));
          int ch = gcol >> 1;
          float hold = __bfloat162float(A[(size_t)row * 2048 + ch]);
          float hnew = gte * hold + (1.f - gte) * fmaxf(v, 0.f);
          Hdst[(size_t)row * 2048 + ch] = __float2bfloat16(hnew);
        }
      }
    }
}

// ---------------------------------------------------------------------------
// Projection GEMM: 32x128 tile (grid 4x128 = 512 blocks, 2/CU), BK=64,
// same XOR swizzle. C fp32 + bias.
// ---------------------------------------------------------------------------
__global__ __launch_bounds__(256) void gemm_proj(
    const __hip_bfloat16* __restrict__ A, const __hip_bfloat16* __restrict__ B,
    float* __restrict__ C, const float* __restrict__ bias) {
  const int K = KDIM;
  __shared__ __align__(16) __hip_bfloat16 As[32 * 64];
  __shared__ __align__(16) __hip_bfloat16 Bs[128 * 64];
  int tid = threadIdx.x;
  int wave = tid >> 6, lane = tid & 63;
  int wr = wave >> 1, wc = wave & 1;
  int bn = blockIdx.y, bm = blockIdx.x;

  int sr8 = lane >> 3, sc8 = lane & 7;
  int frow = lane & 15, q = lane >> 4;

  floatx4 acc[4];
  floatx4 zero = {0.f, 0.f, 0.f, 0.f};
#pragma unroll
  for (int j = 0; j < 4; ++j) acc[j] = zero;

  const __hip_bfloat16* Ab = A + (size_t)bn * 32 * K;
  const __hip_bfloat16* Bb = B + (size_t)bm * 128 * K;

  for (int kb = 0; kb < K; kb += 64) {
    __syncthreads();
    {
      int r = wave * 8 + sr8;           // As: 4 segs x 8 rows
      int gc = sc8 ^ (r & 7);
      async_copy16(Ab + (size_t)r * K + kb + gc * 8, (char*)As + wave * 1024);
    }
#pragma unroll
    for (int it = 0; it < 4; ++it) {
      int seg = wave * 4 + it;          // Bs: 16 segs x 8 rows
      int r = seg * 8 + sr8;
      int gc = sc8 ^ (r & 7);
      async_copy16(Bb + (size_t)r * K + kb + gc * 8, (char*)Bs + seg * 1024);
    }
    __syncthreads();

#pragma unroll
    for (int s = 0; s < 2; ++s) {
      shortx8 af, bf[4];
      {
        int r = wr * 16 + frow;
        af = *(const shortx8*)(As + r * 64 + ((s * 4 + q) ^ (r & 7)) * 8);
      }
#pragma unroll
      for (int j = 0; j < 4; ++j) {
        int r = wc * 64 + j * 16 + frow;
        bf[j] = *(const shortx8*)(Bs + r * 64 + ((s * 4 + q) ^ (r & 7)) * 8);
      }
#pragma unroll
      for (int j = 0; j < 4; ++j)
        acc[j] = __builtin_amdgcn_mfma_f32_16x16x32_bf16(af, bf[j], acc[j],
                                                          0, 0, 0);
    }
  }

  int crow0 = bn * 32 + wr * 16 + q * 4;
  int ccol0 = bm * 128 + wc * 64 + frow;
#pragma unroll
  for (int j = 0; j < 4; ++j) {
    int c = ccol0 + j * 16;
#pragma unroll
    for (int r = 0; r < 4; ++r) {
      int row = crow0 + r;
      C[(size_t)row * PDIM + c] = acc[j][r] + bias[c];
    }
  }
}

// ---------------------------------------------------------------------------
extern "C" void kernel_launch(void* const* d_in, const int* in_sizes, int n_in,
                              void* d_out, int out_size, void* d_ws, size_t ws_size,
                              hipStream_t stream) {
  const int*   chars  = (const int*)d_in[1];
  const float* emb    = (const float*)d_in[2];
  const float* cw[7];
  const float* cb[7];
  for (int i = 0; i < 7; ++i) {
    cw[i] = (const float*)d_in[3 + 2 * i];
    cb[i] = (const float*)d_in[4 + 2 * i];
  }
  const float* hw_w0  = (const float*)d_in[17];
  const float* hw_b0  = (const float*)d_in[18];
  const float* hw_w1  = (const float*)d_in[19];
  const float* hw_b1  = (const float*)d_in[20];
  const float* proj_w = (const float*)d_in[21];
  const float* proj_b = (const float*)d_in[22];
  float* out = (float*)d_out;

  // Workspace (82 MiB):
  //   [0,16)   h   bf16 4096x2048      [16,32) h2  bf16 4096x2048
  //   [32,48)  convWb 512KB + convBc 8KB + embb 8.4KB
  //   [48,64)  w0b  [64,80) w1b  [80,82) pwb
  char* ws = (char*)d_ws;
  __hip_bfloat16* h      = (__hip_bfloat16*)(ws);
  __hip_bfloat16* h2     = (__hip_bfloat16*)(ws + (16ull << 20));
  __hip_bfloat16* convWb = (__hip_bfloat16*)(ws + (32ull << 20));
  float*          convBc = (float*)(ws + (32ull << 20) + 524288);
  __hip_bfloat16* embb   = (__hip_bfloat16*)(ws + (32ull << 20) + 524288 + 8192);
  __hip_bfloat16* w0b    = (__hip_bfloat16*)(ws + (48ull << 20));
  __hip_bfloat16* w1b    = (__hip_bfloat16*)(ws + (64ull << 20));
  __hip_bfloat16* pwb    = (__hip_bfloat16*)(ws + (80ull << 20));

  cvt_hw<<<(HID * KDIM) / 256, 256, 0, stream>>>(hw_w0, w0b);
  cvt_hw<<<(HID * KDIM) / 256, 256, 0, stream>>>(hw_w1, w1b);
  cvt_kernel<<<(PDIM * KDIM) / 256, 256, 0, stream>>>(proj_w, pwb, PDIM * KDIM);
  conv_wprep<<<(262144 + 2048 + 4192 + 255) / 256, 256, 0, stream>>>(
      cw[0], cw[1], cw[2], cw[3], cw[4], cw[5], cw[6],
      cb[0], cb[1], cb[2], cb[3], cb[4], cb[5], cb[6], emb,
      convWb, convBc, embb);

  // Conv: one launch per width class (uniform LDS/template per launch).
  conv_k<1, 4, 72><<<dim3(128, 1), 256, 0, stream>>>(chars, embb, convWb,
                                                     convBc, h, 0);
  conv_k<2, 3, 56><<<dim3(128, 3), 256, 0, stream>>>(chars, embb, convWb,
                                                     convBc, h, 64);
  conv_k<3, 3, 56><<<dim3(128, 12), 256, 0, stream>>>(chars, embb, convWb,
                                                      convBc, h, 256);
  conv_k<4, 3, 56><<<dim3(128, 16), 256, 0, stream>>>(chars, embb, convWb,
                                                      convBc, h, 1024);

  gemm_hw<<<dim3(HID / 128, NTOK / 128), 256, 0, stream>>>(h, w0b, hw_b0, h2);
  gemm_hw<<<dim3(HID / 128, NTOK / 128), 256, 0, stream>>>(h2, w1b, hw_b1, h);
  gemm_proj<<<dim3(PDIM / 128, NTOK / 32), 256, 0, stream>>>(h, pwb, out,
                                                             proj_b);
}